// Round 15
// baseline (7534.138 us; speedup 1.0000x reference)
//
#include <hip/hip_runtime.h>
#include <hip/hip_fp16.h>
#include <cstdint>
#include <cstddef>

#define BATCH 128
#define INF   64
#define OUTF  16
#define SEQ   512
#define FUT   96
#define HID   512
#define G4    2048
#define PROJ  48
#define ECH   4

#define DRG 8
#define DBG 8
#define DUP 64
#define DBP 16

typedef float f32x4 __attribute__((ext_vector_type(4)));

__device__ __forceinline__ float fsigmoid(float x) {
    float e = __builtin_amdgcn_exp2f(-1.4426950408889634f * x);
    return __builtin_amdgcn_rcpf(1.0f + e);
}
__device__ __forceinline__ float ftanh(float x) {
    float e = __builtin_amdgcn_exp2f(2.8853900817779268f * x);
    return 1.0f - 2.0f * __builtin_amdgcn_rcpf(1.0f + e);
}

// LLC-coherent scalar ops (cross-WG traffic)
__device__ __forceinline__ float gload(const float* p) {
    return __hip_atomic_load(p, __ATOMIC_RELAXED, __HIP_MEMORY_SCOPE_AGENT);
}
__device__ __forceinline__ void gstore(float* p, float v) {
    __hip_atomic_store(p, v, __ATOMIC_RELAXED, __HIP_MEMORY_SCOPE_AGENT);
}

// coherent vector gather: sum of 8 partials at p + rr*stride, fixed tree order.
__device__ __forceinline__ f32x4 gsum8(const float* p, size_t stride) {
    f32x4 a0, a1, a2, a3, a4, a5, a6, a7;
    asm volatile(
        "global_load_dwordx4 %0, %8, off sc0 sc1\n\t"
        "global_load_dwordx4 %1, %9, off sc0 sc1\n\t"
        "global_load_dwordx4 %2, %10, off sc0 sc1\n\t"
        "global_load_dwordx4 %3, %11, off sc0 sc1\n\t"
        "global_load_dwordx4 %4, %12, off sc0 sc1\n\t"
        "global_load_dwordx4 %5, %13, off sc0 sc1\n\t"
        "global_load_dwordx4 %6, %14, off sc0 sc1\n\t"
        "global_load_dwordx4 %7, %15, off sc0 sc1\n\t"
        "s_waitcnt vmcnt(0)"
        : "=&v"(a0), "=&v"(a1), "=&v"(a2), "=&v"(a3),
          "=&v"(a4), "=&v"(a5), "=&v"(a6), "=&v"(a7)
        : "v"(p), "v"(p + stride), "v"(p + 2 * stride), "v"(p + 3 * stride),
          "v"(p + 4 * stride), "v"(p + 5 * stride), "v"(p + 6 * stride),
          "v"(p + 7 * stride)
        : "memory");
    return ((a0 + a1) + (a2 + a3)) + ((a4 + a5) + (a6 + a7));
}

// chain barrier among DRG WGs: counter add by tid0, poll with backoff.
__device__ __forceinline__ void bsync(unsigned* ctr, unsigned target, int tid) {
    asm volatile("s_waitcnt vmcnt(0)" ::: "memory");
    __syncthreads();
    if (tid == 0) {
        __hip_atomic_fetch_add(ctr, 1u, __ATOMIC_RELAXED, __HIP_MEMORY_SCOPE_AGENT);
        while (__hip_atomic_load(ctr, __ATOMIC_RELAXED, __HIP_MEMORY_SCOPE_AGENT) < target)
            __builtin_amdgcn_s_sleep(2);
    }
    __syncthreads();
    asm volatile("" ::: "memory");
}

// ---------------- fp16 weight prep ----------------
// WT16p[kp*G4 + row] = half2{ W[row][2kp], W[row][2kp+1] }  (input weights, transposed+packed)
__global__ void k_wtrans16(const float* __restrict__ W, uint32_t* __restrict__ WT16p, int K) {
    int idx = blockIdx.x * 256 + threadIdx.x;
    if (idx >= (K / 2) * G4) return;
    int row = idx & (G4 - 1);
    int kp  = idx >> 11;
    __half2 p = __halves2half2(__float2half(W[(size_t)row * K + 2 * kp]),
                               __float2half(W[(size_t)row * K + 2 * kp + 1]));
    WT16p[idx] = *reinterpret_cast<uint32_t*>(&p);
}
// elementwise f32 -> f16
__global__ void k_cvt16(const float* __restrict__ W, __half* __restrict__ H, int n) {
    int i = blockIdx.x * 256 + threadIdx.x;
    if (i < n) H[i] = __float2half(W[i]);
}

// ---------------- persistent fused encoder (fp16 weight streaming) ----------------
__global__ __launch_bounds__(512) void k_enc(
    const float* __restrict__ x,
    const uint32_t* __restrict__ WT16_0, const __half* __restrict__ Whh16_0,
    const float* __restrict__ bih0, const float* __restrict__ bhh0,
    const float* __restrict__ Whr0,
    const uint32_t* __restrict__ WT16_1, const __half* __restrict__ Whh16_1,
    const float* __restrict__ bih1, const float* __restrict__ bhh1,
    const float* __restrict__ Whr1,
    float* __restrict__ H0x, float* __restrict__ H1,
    float* __restrict__ hs, float* __restrict__ cs,
    unsigned* __restrict__ eflags)
{
    const bool L1w = blockIdx.x >= BATCH;
    const int b = L1w ? blockIdx.x - BATCH : blockIdx.x;
    const int j = threadIdx.x;
    const int wave = j >> 6, lane = j & 63;
    const uint32_t* WT16 = L1w ? WT16_1 : WT16_0;
    const __half* Whh16  = L1w ? Whh16_1 : Whh16_0;
    const float* Whr = L1w ? Whr1 : Whr0;
    const float* bih = L1w ? bih1 : bih0;
    const float* bhh = L1w ? bhh1 : bhh0;
    const int K = L1w ? PROJ : INF;

    __shared__ float whr[PROJ][HID + 4];
    __shared__ __align__(16) float xs[ECH][INF + 4];
    __shared__ __align__(16) float ht_lds[HID];
    __shared__ __align__(16) float h_cur[PROJ];

    for (int idx = j; idx < PROJ * HID; idx += 512) {
        int p = idx >> 9, jj = idx & 511;
        whr[p][jj] = Whr[(size_t)p * HID + jj];
    }
    float bI = bih[j] + bhh[j];
    float bF = bih[j + HID] + bhh[j + HID];
    float bG = bih[j + 2 * HID] + bhh[j + 2 * HID];
    float bO = bih[j + 3 * HID] + bhh[j + 3 * HID];
    float c = 0.f;
    if (j < PROJ) h_cur[j] = 0.f;
    __syncthreads();

    // fp16 Whh row base pointers (rows j, j+512, j+1024, j+1536)
    const __half* whI = Whh16 + (size_t)j * PROJ;
    const __half* whF = Whh16 + (size_t)(j + HID) * PROJ;
    const __half* whG = Whh16 + (size_t)(j + 2 * HID) * PROJ;
    const __half* whO = Whh16 + (size_t)(j + 3 * HID) * PROJ;

    for (int t0 = 0; t0 < SEQ; t0 += ECH) {
        if (!L1w) {
            if (j < INF * ECH) {
                int k = j >> 2, dt = j & 3;
                xs[dt][k] = x[(size_t)b * INF * SEQ + (size_t)k * SEQ + t0 + dt];
            }
        } else {
            if (j == 0) {
                unsigned need = (unsigned)(t0 / ECH) + 1;
                while (__hip_atomic_load(&eflags[b * 16], __ATOMIC_RELAXED,
                                         __HIP_MEMORY_SCOPE_AGENT) < need)
                    __builtin_amdgcn_s_sleep(2);
            }
            __syncthreads();
            asm volatile("" ::: "memory");
            if (j < PROJ * ECH) {
                int dt = j / PROJ, p = j % PROJ;
                xs[dt][p] = gload(&H0x[((size_t)(t0 + dt) * BATCH + b) * PROJ + p]);
            }
        }
        __syncthreads();

        // ---- fused input-gate GEMM (fp16 packed weights, fp32 accumulate) ----
        float a0[ECH], a1[ECH], a2[ECH], a3[ECH];
        #pragma unroll
        for (int dt = 0; dt < ECH; ++dt) { a0[dt] = bI; a1[dt] = bF; }
        for (int kq = 0; kq < K / 4; ++kq) {
            uint32_t di0 = WT16[(size_t)(kq * 2 + 0) * G4 + j];
            uint32_t di1 = WT16[(size_t)(kq * 2 + 1) * G4 + j];
            uint32_t df0 = WT16[(size_t)(kq * 2 + 0) * G4 + HID + j];
            uint32_t df1 = WT16[(size_t)(kq * 2 + 1) * G4 + HID + j];
            const __half* hi0 = (const __half*)&di0;
            const __half* hi1 = (const __half*)&di1;
            const __half* hf0 = (const __half*)&df0;
            const __half* hf1 = (const __half*)&df1;
            #pragma unroll
            for (int dt = 0; dt < ECH; ++dt) {
                float4 xv = *reinterpret_cast<const float4*>(&xs[dt][kq * 4]);
                a0[dt] += __half2float(hi0[0])*xv.x + __half2float(hi0[1])*xv.y
                        + __half2float(hi1[0])*xv.z + __half2float(hi1[1])*xv.w;
                a1[dt] += __half2float(hf0[0])*xv.x + __half2float(hf0[1])*xv.y
                        + __half2float(hf1[0])*xv.z + __half2float(hf1[1])*xv.w;
            }
        }
        #pragma unroll
        for (int dt = 0; dt < ECH; ++dt) { a2[dt] = bG; a3[dt] = bO; }
        for (int kq = 0; kq < K / 4; ++kq) {
            uint32_t dg0 = WT16[(size_t)(kq * 2 + 0) * G4 + 2 * HID + j];
            uint32_t dg1 = WT16[(size_t)(kq * 2 + 1) * G4 + 2 * HID + j];
            uint32_t do0 = WT16[(size_t)(kq * 2 + 0) * G4 + 3 * HID + j];
            uint32_t do1 = WT16[(size_t)(kq * 2 + 1) * G4 + 3 * HID + j];
            const __half* hg0 = (const __half*)&dg0;
            const __half* hg1 = (const __half*)&dg1;
            const __half* ho0 = (const __half*)&do0;
            const __half* ho1 = (const __half*)&do1;
            #pragma unroll
            for (int dt = 0; dt < ECH; ++dt) {
                float4 xv = *reinterpret_cast<const float4*>(&xs[dt][kq * 4]);
                a2[dt] += __half2float(hg0[0])*xv.x + __half2float(hg0[1])*xv.y
                        + __half2float(hg1[0])*xv.z + __half2float(hg1[1])*xv.w;
                a3[dt] += __half2float(ho0[0])*xv.x + __half2float(ho0[1])*xv.y
                        + __half2float(ho1[0])*xv.z + __half2float(ho1[1])*xv.w;
            }
        }

        // ---- recurrent steps: fp16 Whh streamed per dt (half the bytes) ----
        #pragma unroll
        for (int dt = 0; dt < ECH; ++dt) {
            float ai = a0[dt], af = a1[dt], ag = a2[dt], ao = a3[dt];
            #pragma unroll
            for (int k4 = 0; k4 < 12; ++k4) {
                float2 rI = *reinterpret_cast<const float2*>(whI + 4 * k4);
                float2 rF = *reinterpret_cast<const float2*>(whF + 4 * k4);
                float2 rG = *reinterpret_cast<const float2*>(whG + 4 * k4);
                float2 rO = *reinterpret_cast<const float2*>(whO + 4 * k4);
                const __half* hI = (const __half*)&rI;
                const __half* hF = (const __half*)&rF;
                const __half* hG = (const __half*)&rG;
                const __half* hO = (const __half*)&rO;
                float4 h4 = *reinterpret_cast<const float4*>(&h_cur[4 * k4]);
                ai += __half2float(hI[0])*h4.x + __half2float(hI[1])*h4.y
                    + __half2float(hI[2])*h4.z + __half2float(hI[3])*h4.w;
                af += __half2float(hF[0])*h4.x + __half2float(hF[1])*h4.y
                    + __half2float(hF[2])*h4.z + __half2float(hF[3])*h4.w;
                ag += __half2float(hG[0])*h4.x + __half2float(hG[1])*h4.y
                    + __half2float(hG[2])*h4.z + __half2float(hG[3])*h4.w;
                ao += __half2float(hO[0])*h4.x + __half2float(hO[1])*h4.y
                    + __half2float(hO[2])*h4.z + __half2float(hO[3])*h4.w;
            }
            float si = fsigmoid(ai), sf = fsigmoid(af), so = fsigmoid(ao), tg = ftanh(ag);
            c = sf * c + si * tg;
            ht_lds[j] = so * ftanh(c);
            __syncthreads();
            float rq[6];
            #pragma unroll
            for (int q = 0; q < 6; ++q) {
                int p = wave * 6 + q;
                float s = 0.f;
                #pragma unroll
                for (int m = 0; m < 8; ++m)
                    s += whr[p][lane + 64 * m] * ht_lds[lane + 64 * m];
                #pragma unroll
                for (int o = 32; o; o >>= 1) s += __shfl_xor(s, o, 64);
                rq[q] = s;
            }
            if (lane == 0) {
                int t = t0 + dt;
                #pragma unroll
                for (int q = 0; q < 6; ++q) {
                    int p = wave * 6 + q;
                    float v = rq[q];
                    h_cur[p] = v;
                    if (!L1w) gstore(&H0x[((size_t)t * BATCH + b) * PROJ + p], v);
                    else      H1[((size_t)t * BATCH + b) * PROJ + p] = v;
                }
            }
            __syncthreads();
        }
        if (!L1w) {
            asm volatile("s_waitcnt vmcnt(0)" ::: "memory");
            __syncthreads();
            if (j == 0)
                __hip_atomic_store(&eflags[b * 16], (unsigned)(t0 / ECH) + 1,
                                   __ATOMIC_RELAXED, __HIP_MEMORY_SCOPE_AGENT);
        }
    }
    cs[((size_t)(L1w ? BATCH : 0) + b) * HID + j] = c;
    if (j < PROJ) hs[((size_t)(L1w ? BATCH : 0) + b) * PROJ + j] = h_cur[j];
}

// ---------------- persistent spill-free decoder: 64 WGs, 2 syncs/step ----------------
__global__ __launch_bounds__(512) void k_decP(
    const float* __restrict__ xdec,
    const float* __restrict__ Wih0, const float* __restrict__ Whh0,
    const float* __restrict__ bih0, const float* __restrict__ bhh0,
    const float* __restrict__ Whr0,
    const float* __restrict__ Wih1, const float* __restrict__ Whh1,
    const float* __restrict__ bih1, const float* __restrict__ bhh1,
    const float* __restrict__ Whr1,
    const float* __restrict__ hs, const float* __restrict__ cs,
    const float* __restrict__ xin,
    float* __restrict__ PPa, float* __restrict__ PPb,
    float* __restrict__ PRED,
    unsigned* __restrict__ bar)
{
    const int bg = blockIdx.x & 7, rg = blockIdx.x >> 3;
    const int tid = threadIdx.x;
    const int kq = tid & 3, rhalf = tid >> 2;
    const int u2 = tid >> 3, b2 = tid & 7;
    const int uglob = rg * DUP + u2;
    const int w = tid >> 6, lane = tid & 63;
    const size_t PSTR = (size_t)BATCH * PROJ;
    const size_t DPP  = (size_t)DRG * PSTR;

    __shared__ __align__(16) float inp0[DBP][120];
    __shared__ __align__(16) float h1b[DBP][52];
    __shared__ __align__(16) float h0n[DBP][52];
    __shared__ float xch[4][DUP][17];
    __shared__ float htl[DBP][68];
    __shared__ float wslT0[DUP][52];
    __shared__ float wslT1[DUP][52];

    for (int i = tid; i < PROJ * DUP; i += 512) {
        int p = i >> 6, uu = i & 63;
        wslT0[uu][p] = Whr0[(size_t)p * HID + rg * DUP + uu];
        wslT1[uu][p] = Whr1[(size_t)p * HID + rg * DUP + uu];
    }
    float bs0[4], bs1[4];
    #pragma unroll
    for (int gg = 0; gg < 4; ++gg) {
        bs0[gg] = bih0[gg * HID + uglob] + bhh0[gg * HID + uglob];
        bs1[gg] = bih1[gg * HID + uglob] + bhh1[gg * HID + uglob];
    }
    float c0[2], c1[2];
    #pragma unroll
    for (int hh = 0; hh < 2; ++hh) {
        int bglob = bg * DBP + b2 + 8 * hh;
        c0[hh] = cs[(size_t)bglob * HID + uglob];
        c1[hh] = cs[(size_t)(BATCH + bglob) * HID + uglob];
    }
    __syncthreads();

    unsigned* ctr = bar + bg * 64;
    unsigned phase = 0;

    for (int t = 0; t < FUT; ++t) {
        const float* ppaR = PPa + (size_t)((t - 1) & 1) * DPP;
        float*       ppaW = PPa + (size_t)(t & 1) * DPP;
        const float* ppbR = PPb + (size_t)((t - 1) & 1) * DPP;
        float*       ppbW = PPb + (size_t)(t & 1) * DPP;

        // ================= PHASE A =================
        if (t == 0) {
            for (int i = tid; i < DBP * PROJ; i += 512) {
                int b = i / PROJ, p = i % PROJ;
                int bglob = bg * DBP + b;
                inp0[b][p]      = hs[(size_t)bglob * PROJ + p];
                inp0[b][48 + p] = xin[(size_t)bglob * INF * SEQ + (size_t)p * SEQ + (SEQ - 1)];
                h1b[b][p]       = hs[(size_t)(BATCH + bglob) * PROJ + p];
            }
            if (tid < DBP * OUTF) {
                int b = tid >> 4, f = tid & 15;
                inp0[b][96 + f] = xdec[(size_t)(bg * DBP + b) * (OUTF * FUT) + (size_t)f * FUT];
            }
        } else {
            if (tid < 192) {
                int b = tid / 12, p = (tid % 12) * 4;
                int bglob = bg * DBP + b;
                f32x4 s = gsum8(ppaR + (size_t)bglob * PROJ + p, PSTR);
                *reinterpret_cast<f32x4*>(&inp0[b][p]) = s;
            } else if (tid < 384) {
                int idx = tid - 192;
                int b = idx / 12, p = (idx % 12) * 4;
                int bglob = bg * DBP + b;
                f32x4 s = gsum8(ppbR + (size_t)bglob * PROJ + p, PSTR);
                *reinterpret_cast<f32x4*>(&inp0[b][48 + p]) = s;
                *reinterpret_cast<f32x4*>(&h1b[b][p]) = s;
                if (rg == 0)
                    *reinterpret_cast<f32x4*>(&PRED[((size_t)(t - 1) * BATCH + bglob) * PROJ + p]) = s;
            } else {
                #pragma unroll
                for (int rep = 0; rep < 2; ++rep) {
                    int i2 = (tid - 384) + rep * 128;
                    int b = i2 >> 4, f = i2 & 15;
                    inp0[b][96 + f] = xdec[(size_t)(bg * DBP + b) * (OUTF * FUT) + (size_t)f * FUT + t];
                }
            }
        }
        __syncthreads();

        #pragma unroll
        for (int p = 0; p < 2; ++p) {
            int rid = p * 128 + rhalf;
            int g = rid >> 6, u = rid & 63;
            int grow = g * HID + rg * DUP + u;
            float wv[28];
            #pragma unroll
            for (int kk = 0; kk < 28; ++kk) {
                int k = kq * 28 + kk;
                wv[kk] = (k < 48) ? Whh0[(size_t)grow * 48 + k]
                                  : Wih0[(size_t)grow * 64 + (k - 48)];
            }
            float acc[DBP];
            #pragma unroll
            for (int b = 0; b < DBP; ++b) acc[b] = 0.f;
            const float* srcA = &inp0[0][0] + kq * 28;
            #pragma unroll
            for (int i4 = 0; i4 < 7; ++i4) {
                float w0 = wv[i4*4], w1 = wv[i4*4+1], w2 = wv[i4*4+2], w3 = wv[i4*4+3];
                #pragma unroll
                for (int b = 0; b < DBP; ++b) {
                    float4 xv = *reinterpret_cast<const float4*>(&srcA[b * 120 + i4 * 4]);
                    acc[b] += w0*xv.x + w1*xv.y + w2*xv.z + w3*xv.w;
                }
            }
            #pragma unroll
            for (int b = 0; b < DBP; ++b) {
                acc[b] += __shfl_xor(acc[b], 1, 64);
                acc[b] += __shfl_xor(acc[b], 2, 64);
            }
            if (kq == 0) {
                #pragma unroll
                for (int b = 0; b < DBP; ++b) xch[g][u][b] = acc[b];
            }
        }
        __syncthreads();
        #pragma unroll
        for (int hh = 0; hh < 2; ++hh) {
            int b = b2 + 8 * hh;
            float gi = xch[0][u2][b] + bs0[0];
            float gf = xch[1][u2][b] + bs0[1];
            float gc = xch[2][u2][b] + bs0[2];
            float go = xch[3][u2][b] + bs0[3];
            float si = fsigmoid(gi), sf = fsigmoid(gf), so = fsigmoid(go), tg = ftanh(gc);
            c0[hh] = sf * c0[hh] + si * tg;
            htl[b][u2] = so * ftanh(c0[hh]);
        }
        __syncthreads();
        if (lane < PROJ) {
            #pragma unroll
            for (int bb = 0; bb < 2; ++bb) {
                int b = 2 * w + bb;
                float s = 0.f;
                #pragma unroll
                for (int u4 = 0; u4 < 16; ++u4) {
                    float4 hv = *reinterpret_cast<const float4*>(&htl[b][u4 * 4]);
                    s += wslT0[u4*4+0][lane]*hv.x + wslT0[u4*4+1][lane]*hv.y
                       + wslT0[u4*4+2][lane]*hv.z + wslT0[u4*4+3][lane]*hv.w;
                }
                gstore(&ppaW[(size_t)rg * PSTR + (size_t)(bg * DBP + b) * PROJ + lane], s);
            }
        }
        phase += 1;
        bsync(ctr, phase * DRG, tid);

        // ================= PHASE B =================
        if (tid < 192) {
            int b = tid / 12, p = (tid % 12) * 4;
            f32x4 s = gsum8(ppaW + (size_t)(bg * DBP + b) * PROJ + p, PSTR);
            *reinterpret_cast<f32x4*>(&h0n[b][p]) = s;
        }
        __syncthreads();

        #pragma unroll
        for (int p = 0; p < 2; ++p) {
            int rid = p * 128 + rhalf;
            int g = rid >> 6, u = rid & 63;
            int grow = g * HID + rg * DUP + u;
            float wv[24];
            #pragma unroll
            for (int kk = 0; kk < 24; ++kk) {
                int k = kq * 24 + kk;
                wv[kk] = (k < 48) ? Whh1[(size_t)grow * 48 + k]
                                  : Wih1[(size_t)grow * 48 + (k - 48)];
            }
            const float* srcB = (kq < 2) ? (&h1b[0][0] + kq * 24)
                                         : (&h0n[0][0] + (kq - 2) * 24);
            float acc[DBP];
            #pragma unroll
            for (int b = 0; b < DBP; ++b) acc[b] = 0.f;
            #pragma unroll
            for (int i4 = 0; i4 < 6; ++i4) {
                float w0 = wv[i4*4], w1 = wv[i4*4+1], w2 = wv[i4*4+2], w3 = wv[i4*4+3];
                #pragma unroll
                for (int b = 0; b < DBP; ++b) {
                    float4 xv = *reinterpret_cast<const float4*>(&srcB[b * 52 + i4 * 4]);
                    acc[b] += w0*xv.x + w1*xv.y + w2*xv.z + w3*xv.w;
                }
            }
            #pragma unroll
            for (int b = 0; b < DBP; ++b) {
                acc[b] += __shfl_xor(acc[b], 1, 64);
                acc[b] += __shfl_xor(acc[b], 2, 64);
            }
            if (kq == 0) {
                #pragma unroll
                for (int b = 0; b < DBP; ++b) xch[g][u][b] = acc[b];
            }
        }
        __syncthreads();
        #pragma unroll
        for (int hh = 0; hh < 2; ++hh) {
            int b = b2 + 8 * hh;
            float gi = xch[0][u2][b] + bs1[0];
            float gf = xch[1][u2][b] + bs1[1];
            float gc = xch[2][u2][b] + bs1[2];
            float go = xch[3][u2][b] + bs1[3];
            float si = fsigmoid(gi), sf = fsigmoid(gf), so = fsigmoid(go), tg = ftanh(gc);
            c1[hh] = sf * c1[hh] + si * tg;
            htl[b][u2] = so * ftanh(c1[hh]);
        }
        __syncthreads();
        if (lane < PROJ) {
            #pragma unroll
            for (int bb = 0; bb < 2; ++bb) {
                int b = 2 * w + bb;
                float s = 0.f;
                #pragma unroll
                for (int u4 = 0; u4 < 16; ++u4) {
                    float4 hv = *reinterpret_cast<const float4*>(&htl[b][u4 * 4]);
                    s += wslT1[u4*4+0][lane]*hv.x + wslT1[u4*4+1][lane]*hv.y
                       + wslT1[u4*4+2][lane]*hv.z + wslT1[u4*4+3][lane]*hv.w;
                }
                gstore(&ppbW[(size_t)rg * PSTR + (size_t)(bg * DBP + b) * PROJ + lane], s);
            }
        }
        phase += 1;
        bsync(ctr, phase * DRG, tid);
    }

    if (tid < 2 * PROJ) {
        int bb = tid / PROJ, p = tid % PROJ;
        int bglob = bg * DBP + 2 * rg + bb;
        const float* ppbF = PPb + (size_t)((FUT - 1) & 1) * DPP;
        float s = 0.f;
        #pragma unroll
        for (int rr = 0; rr < DRG; ++rr)
            s += gload(&ppbF[(size_t)rr * PSTR + (size_t)bglob * PROJ + p]);
        PRED[((size_t)(FUT - 1) * BATCH + bglob) * PROJ + p] = s;
    }
}

// ---------------- basis contractions ----------------
__global__ void k_final(const float* __restrict__ theta, const float* __restrict__ H1,
                        const float* __restrict__ PRED, float* __restrict__ out)
{
    int b = blockIdx.x;
    __shared__ float th[2 * PROJ];
    if (threadIdx.x < 2 * PROJ) th[threadIdx.x] = theta[(size_t)b * 2 * PROJ + threadIdx.x];
    __syncthreads();
    for (int t = threadIdx.x; t < SEQ; t += 256) {
        float s = 0.f;
        #pragma unroll
        for (int p = 0; p < PROJ; ++p) s += th[PROJ + p] * H1[((size_t)t * BATCH + b) * PROJ + p];
        out[(size_t)b * SEQ + t] = s;
    }
    for (int t = threadIdx.x; t < FUT; t += 256) {
        float s = 0.f;
        #pragma unroll
        for (int p = 0; p < PROJ; ++p) s += th[p] * PRED[((size_t)t * BATCH + b) * PROJ + p];
        out[(size_t)BATCH * SEQ + (size_t)b * FUT + t] = s;
    }
}

extern "C" void kernel_launch(void* const* d_in, const int* in_sizes, int n_in,
                              void* d_out, int out_size, void* d_ws, size_t ws_size,
                              hipStream_t stream)
{
    (void)in_sizes; (void)n_in; (void)out_size; (void)ws_size;
    const float* theta = (const float*)d_in[0];
    const float* xin   = (const float*)d_in[1];
    const float* xdec  = (const float*)d_in[2];
    const float* eW0i = (const float*)d_in[3];
    const float* eW0h = (const float*)d_in[4];
    const float* eb0i = (const float*)d_in[5];
    const float* eb0h = (const float*)d_in[6];
    const float* eW0r = (const float*)d_in[7];
    const float* eW1i = (const float*)d_in[8];
    const float* eW1h = (const float*)d_in[9];
    const float* eb1i = (const float*)d_in[10];
    const float* eb1h = (const float*)d_in[11];
    const float* eW1r = (const float*)d_in[12];
    const float* dW0i = (const float*)d_in[13];
    const float* dW0h = (const float*)d_in[14];
    const float* db0i = (const float*)d_in[15];
    const float* db0h = (const float*)d_in[16];
    const float* dW0r = (const float*)d_in[17];
    const float* dW1i = (const float*)d_in[18];
    const float* dW1h = (const float*)d_in[19];
    const float* db1i = (const float*)d_in[20];
    const float* db1h = (const float*)d_in[21];
    const float* dW1r = (const float*)d_in[22];

    float* ws = (float*)d_ws;
    size_t off = 0;
    float* H0x  = ws + off; off += (size_t)SEQ * BATCH * PROJ;
    float* H1   = ws + off; off += (size_t)SEQ * BATCH * PROJ;
    float* PRED = ws + off; off += (size_t)FUT * BATCH * PROJ;
    float* hs   = ws + off; off += (size_t)2 * BATCH * PROJ;
    float* cs   = ws + off; off += (size_t)2 * BATCH * HID;
    uint32_t* WT16_0 = (uint32_t*)(ws + off); off += (size_t)(INF / 2) * G4;
    uint32_t* WT16_1 = (uint32_t*)(ws + off); off += (size_t)(PROJ / 2) * G4;
    __half* Whh16_0  = (__half*)(ws + off);   off += (size_t)G4 * PROJ / 2;
    __half* Whh16_1  = (__half*)(ws + off);   off += (size_t)G4 * PROJ / 2;
    const size_t DPP = (size_t)DRG * BATCH * PROJ;
    float* PPa  = ws + off; off += 2 * DPP;
    float* PPb  = ws + off; off += 2 * DPP;
    off = (off + 63) & ~(size_t)63;
    unsigned* eflags = (unsigned*)(ws + off); off += BATCH * 16;
    unsigned* bar    = (unsigned*)(ws + off); off += DBG * 64;

    hipMemsetAsync(eflags, 0, (BATCH * 16 + DBG * 64) * sizeof(unsigned), stream);
    k_wtrans16<<<((INF / 2) * G4 + 255) / 256, 256, 0, stream>>>(eW0i, WT16_0, INF);
    k_wtrans16<<<((PROJ / 2) * G4 + 255) / 256, 256, 0, stream>>>(eW1i, WT16_1, PROJ);
    k_cvt16<<<(G4 * PROJ + 255) / 256, 256, 0, stream>>>(eW0h, Whh16_0, G4 * PROJ);
    k_cvt16<<<(G4 * PROJ + 255) / 256, 256, 0, stream>>>(eW1h, Whh16_1, G4 * PROJ);
    k_enc<<<2 * BATCH, 512, 0, stream>>>(xin,
                                         WT16_0, Whh16_0, eb0i, eb0h, eW0r,
                                         WT16_1, Whh16_1, eb1i, eb1h, eW1r,
                                         H0x, H1, hs, cs, eflags);
    k_decP<<<DRG * DBG, 512, 0, stream>>>(xdec, dW0i, dW0h, db0i, db0h, dW0r,
                                          dW1i, dW1h, db1i, db1h, dW1r,
                                          hs, cs, xin, PPa, PPb, PRED, bar);
    k_final<<<BATCH, 256, 0, stream>>>(theta, H1, PRED, (float*)d_out);
}

// Round 16
// 5506.832 us; speedup vs baseline: 1.3681x; 1.3681x over previous
//
#include <hip/hip_runtime.h>
#include <cstdint>
#include <cstddef>

#define BATCH 128
#define INF   64
#define OUTF  16
#define SEQ   512
#define FUT   96
#define HID   512
#define G4    2048
#define PROJ  48
#define ECH   4

#define DRG 8
#define DBG 8
#define DUP 64
#define DBP 16

typedef float f32x4 __attribute__((ext_vector_type(4)));

__device__ __forceinline__ float fsigmoid(float x) {
    float e = __builtin_amdgcn_exp2f(-1.4426950408889634f * x);
    return __builtin_amdgcn_rcpf(1.0f + e);
}
__device__ __forceinline__ float ftanh(float x) {
    float e = __builtin_amdgcn_exp2f(2.8853900817779268f * x);
    return 1.0f - 2.0f * __builtin_amdgcn_rcpf(1.0f + e);
}

// LLC-coherent scalar ops (cross-WG traffic)
__device__ __forceinline__ float gload(const float* p) {
    return __hip_atomic_load(p, __ATOMIC_RELAXED, __HIP_MEMORY_SCOPE_AGENT);
}
__device__ __forceinline__ void gstore(float* p, float v) {
    __hip_atomic_store(p, v, __ATOMIC_RELAXED, __HIP_MEMORY_SCOPE_AGENT);
}

// coherent vector gather: sum of 8 partials at p + rr*stride, fixed tree order.
__device__ __forceinline__ f32x4 gsum8(const float* p, size_t stride) {
    f32x4 a0, a1, a2, a3, a4, a5, a6, a7;
    asm volatile(
        "global_load_dwordx4 %0, %8, off sc0 sc1\n\t"
        "global_load_dwordx4 %1, %9, off sc0 sc1\n\t"
        "global_load_dwordx4 %2, %10, off sc0 sc1\n\t"
        "global_load_dwordx4 %3, %11, off sc0 sc1\n\t"
        "global_load_dwordx4 %4, %12, off sc0 sc1\n\t"
        "global_load_dwordx4 %5, %13, off sc0 sc1\n\t"
        "global_load_dwordx4 %6, %14, off sc0 sc1\n\t"
        "global_load_dwordx4 %7, %15, off sc0 sc1\n\t"
        "s_waitcnt vmcnt(0)"
        : "=&v"(a0), "=&v"(a1), "=&v"(a2), "=&v"(a3),
          "=&v"(a4), "=&v"(a5), "=&v"(a6), "=&v"(a7)
        : "v"(p), "v"(p + stride), "v"(p + 2 * stride), "v"(p + 3 * stride),
          "v"(p + 4 * stride), "v"(p + 5 * stride), "v"(p + 6 * stride),
          "v"(p + 7 * stride)
        : "memory");
    return ((a0 + a1) + (a2 + a3)) + ((a4 + a5) + (a6 + a7));
}

// chain barrier among DRG WGs: counter add by tid0, poll with backoff.
__device__ __forceinline__ void bsync(unsigned* ctr, unsigned target, int tid) {
    asm volatile("s_waitcnt vmcnt(0)" ::: "memory");
    __syncthreads();
    if (tid == 0) {
        __hip_atomic_fetch_add(ctr, 1u, __ATOMIC_RELAXED, __HIP_MEMORY_SCOPE_AGENT);
        while (__hip_atomic_load(ctr, __ATOMIC_RELAXED, __HIP_MEMORY_SCOPE_AGENT) < target)
            __builtin_amdgcn_s_sleep(2);
    }
    __syncthreads();
    asm volatile("" ::: "memory");
}

// ---------------- guarded transpose W[R][C] -> WT[C][R] ----------------
__global__ void k_wtrans(const float* __restrict__ W, float* __restrict__ WT,
                         int R, int C) {
    __shared__ float tile[32][33];
    int r0 = blockIdx.x * 32, c0 = blockIdx.y * 32;
    int tx = threadIdx.x, ty = threadIdx.y;
    #pragma unroll
    for (int i = 0; i < 4; ++i) {
        int r = r0 + ty + 8 * i;
        if (r < R && c0 + tx < C) tile[ty + 8 * i][tx] = W[(size_t)r * C + c0 + tx];
    }
    __syncthreads();
    #pragma unroll
    for (int i = 0; i < 4; ++i) {
        int c = c0 + ty + 8 * i;
        if (c < C && r0 + tx < R) WT[(size_t)c * R + r0 + tx] = tile[tx][ty + 8 * i];
    }
}

// ---------------- persistent fused encoder (R14-fp32 + merged input GEMM) ----------------
__global__ __launch_bounds__(512) void k_enc(
    const float* __restrict__ x,
    const float* __restrict__ WT0, const float* __restrict__ Whh0,
    const float* __restrict__ bih0, const float* __restrict__ bhh0,
    const float* __restrict__ Whr0,
    const float* __restrict__ WT1, const float* __restrict__ Whh1,
    const float* __restrict__ bih1, const float* __restrict__ bhh1,
    const float* __restrict__ Whr1,
    float* __restrict__ H0x, float* __restrict__ H1,
    float* __restrict__ hs, float* __restrict__ cs,
    unsigned* __restrict__ eflags)
{
    const bool L1w = blockIdx.x >= BATCH;
    const int b = L1w ? blockIdx.x - BATCH : blockIdx.x;
    const int j = threadIdx.x;
    const int wave = j >> 6, lane = j & 63;
    const float* WT  = L1w ? WT1 : WT0;
    const float* Whh = L1w ? Whh1 : Whh0;
    const float* Whr = L1w ? Whr1 : Whr0;
    const float* bih = L1w ? bih1 : bih0;
    const float* bhh = L1w ? bhh1 : bhh0;
    const int K = L1w ? PROJ : INF;

    __shared__ float whr[PROJ][HID + 4];
    __shared__ __align__(16) float xs[ECH][INF + 4];
    __shared__ __align__(16) float ht_lds[HID];
    __shared__ __align__(16) float h_cur[PROJ];

    float wI[PROJ], wF[PROJ], wG[PROJ], wO[PROJ];
    #pragma unroll
    for (int k4 = 0; k4 < 12; ++k4) {
        float4 vi = *reinterpret_cast<const float4*>(&Whh[(size_t)j * PROJ + 4 * k4]);
        float4 vf = *reinterpret_cast<const float4*>(&Whh[(size_t)(j + HID) * PROJ + 4 * k4]);
        float4 vg = *reinterpret_cast<const float4*>(&Whh[(size_t)(j + 2 * HID) * PROJ + 4 * k4]);
        float4 vo = *reinterpret_cast<const float4*>(&Whh[(size_t)(j + 3 * HID) * PROJ + 4 * k4]);
        wI[4*k4+0]=vi.x; wI[4*k4+1]=vi.y; wI[4*k4+2]=vi.z; wI[4*k4+3]=vi.w;
        wF[4*k4+0]=vf.x; wF[4*k4+1]=vf.y; wF[4*k4+2]=vf.z; wF[4*k4+3]=vf.w;
        wG[4*k4+0]=vg.x; wG[4*k4+1]=vg.y; wG[4*k4+2]=vg.z; wG[4*k4+3]=vg.w;
        wO[4*k4+0]=vo.x; wO[4*k4+1]=vo.y; wO[4*k4+2]=vo.z; wO[4*k4+3]=vo.w;
    }
    for (int idx = j; idx < PROJ * HID; idx += 512) {
        int p = idx >> 9, jj = idx & 511;
        whr[p][jj] = Whr[(size_t)p * HID + jj];
    }
    float bI = bih[j] + bhh[j];
    float bF = bih[j + HID] + bhh[j + HID];
    float bG = bih[j + 2 * HID] + bhh[j + 2 * HID];
    float bO = bih[j + 3 * HID] + bhh[j + 3 * HID];
    float c = 0.f;
    if (j < PROJ) h_cur[j] = 0.f;
    __syncthreads();

    for (int t0 = 0; t0 < SEQ; t0 += ECH) {
        if (!L1w) {
            if (j < INF * ECH) {
                int k = j >> 2, dt = j & 3;
                xs[dt][k] = x[(size_t)b * INF * SEQ + (size_t)k * SEQ + t0 + dt];
            }
        } else {
            if (j == 0) {
                unsigned need = (unsigned)(t0 / ECH) + 1;
                while (__hip_atomic_load(&eflags[b * 16], __ATOMIC_RELAXED,
                                         __HIP_MEMORY_SCOPE_AGENT) < need)
                    __builtin_amdgcn_s_sleep(2);
            }
            __syncthreads();
            asm volatile("" ::: "memory");
            if (j < PROJ * ECH) {
                int dt = j / PROJ, p = j % PROJ;
                xs[dt][p] = gload(&H0x[((size_t)(t0 + dt) * BATCH + b) * PROJ + p]);
            }
        }
        __syncthreads();

        // ---- merged input-gate GEMM: 16 weight loads per kq (deeper MLP) ----
        float a0[ECH], a1[ECH], a2[ECH], a3[ECH];
        #pragma unroll
        for (int dt = 0; dt < ECH; ++dt) {
            a0[dt] = bI; a1[dt] = bF; a2[dt] = bG; a3[dt] = bO;
        }
        for (int kq = 0; kq < K / 4; ++kq) {
            float wi0 = WT[(size_t)(kq*4+0) * G4 + j];
            float wi1 = WT[(size_t)(kq*4+1) * G4 + j];
            float wi2 = WT[(size_t)(kq*4+2) * G4 + j];
            float wi3 = WT[(size_t)(kq*4+3) * G4 + j];
            float wf0 = WT[(size_t)(kq*4+0) * G4 + HID + j];
            float wf1 = WT[(size_t)(kq*4+1) * G4 + HID + j];
            float wf2 = WT[(size_t)(kq*4+2) * G4 + HID + j];
            float wf3 = WT[(size_t)(kq*4+3) * G4 + HID + j];
            float wg0 = WT[(size_t)(kq*4+0) * G4 + 2 * HID + j];
            float wg1 = WT[(size_t)(kq*4+1) * G4 + 2 * HID + j];
            float wg2 = WT[(size_t)(kq*4+2) * G4 + 2 * HID + j];
            float wg3 = WT[(size_t)(kq*4+3) * G4 + 2 * HID + j];
            float wo0 = WT[(size_t)(kq*4+0) * G4 + 3 * HID + j];
            float wo1 = WT[(size_t)(kq*4+1) * G4 + 3 * HID + j];
            float wo2 = WT[(size_t)(kq*4+2) * G4 + 3 * HID + j];
            float wo3 = WT[(size_t)(kq*4+3) * G4 + 3 * HID + j];
            #pragma unroll
            for (int dt = 0; dt < ECH; ++dt) {
                float4 xv = *reinterpret_cast<const float4*>(&xs[dt][kq * 4]);
                a0[dt] += wi0*xv.x + wi1*xv.y + wi2*xv.z + wi3*xv.w;
                a1[dt] += wf0*xv.x + wf1*xv.y + wf2*xv.z + wf3*xv.w;
                a2[dt] += wg0*xv.x + wg1*xv.y + wg2*xv.z + wg3*xv.w;
                a3[dt] += wo0*xv.x + wo1*xv.y + wo2*xv.z + wo3*xv.w;
            }
        }

        #pragma unroll
        for (int dt = 0; dt < ECH; ++dt) {
            float ai = a0[dt], af = a1[dt], ag = a2[dt], ao = a3[dt];
            #pragma unroll
            for (int k4 = 0; k4 < 12; ++k4) {
                float4 h4 = *reinterpret_cast<const float4*>(&h_cur[4 * k4]);
                ai += wI[4*k4+0]*h4.x + wI[4*k4+1]*h4.y + wI[4*k4+2]*h4.z + wI[4*k4+3]*h4.w;
                af += wF[4*k4+0]*h4.x + wF[4*k4+1]*h4.y + wF[4*k4+2]*h4.z + wF[4*k4+3]*h4.w;
                ag += wG[4*k4+0]*h4.x + wG[4*k4+1]*h4.y + wG[4*k4+2]*h4.z + wG[4*k4+3]*h4.w;
                ao += wO[4*k4+0]*h4.x + wO[4*k4+1]*h4.y + wO[4*k4+2]*h4.z + wO[4*k4+3]*h4.w;
            }
            float si = fsigmoid(ai), sf = fsigmoid(af), so = fsigmoid(ao), tg = ftanh(ag);
            c = sf * c + si * tg;
            ht_lds[j] = so * ftanh(c);
            __syncthreads();
            float rq[6];
            #pragma unroll
            for (int q = 0; q < 6; ++q) {
                int p = wave * 6 + q;
                float s = 0.f;
                #pragma unroll
                for (int m = 0; m < 8; ++m)
                    s += whr[p][lane + 64 * m] * ht_lds[lane + 64 * m];
                #pragma unroll
                for (int o = 32; o; o >>= 1) s += __shfl_xor(s, o, 64);
                rq[q] = s;
            }
            if (lane == 0) {
                int t = t0 + dt;
                #pragma unroll
                for (int q = 0; q < 6; ++q) {
                    int p = wave * 6 + q;
                    float v = rq[q];
                    h_cur[p] = v;
                    if (!L1w) gstore(&H0x[((size_t)t * BATCH + b) * PROJ + p], v);
                    else      H1[((size_t)t * BATCH + b) * PROJ + p] = v;
                }
            }
            __syncthreads();
        }
        if (!L1w) {
            asm volatile("s_waitcnt vmcnt(0)" ::: "memory");
            __syncthreads();
            if (j == 0)
                __hip_atomic_store(&eflags[b * 16], (unsigned)(t0 / ECH) + 1,
                                   __ATOMIC_RELAXED, __HIP_MEMORY_SCOPE_AGENT);
        }
    }
    cs[((size_t)(L1w ? BATCH : 0) + b) * HID + j] = c;
    if (j < PROJ) hs[((size_t)(L1w ? BATCH : 0) + b) * PROJ + j] = h_cur[j];
}

// ---------------- persistent spill-free decoder: 64 WGs, 2 syncs/step ----------------
__global__ __launch_bounds__(512) void k_decP(
    const float* __restrict__ xdec,
    const float* __restrict__ Wih0, const float* __restrict__ Whh0,
    const float* __restrict__ bih0, const float* __restrict__ bhh0,
    const float* __restrict__ Whr0,
    const float* __restrict__ Wih1, const float* __restrict__ Whh1,
    const float* __restrict__ bih1, const float* __restrict__ bhh1,
    const float* __restrict__ Whr1,
    const float* __restrict__ hs, const float* __restrict__ cs,
    const float* __restrict__ xin,
    float* __restrict__ PPa, float* __restrict__ PPb,
    float* __restrict__ PRED,
    unsigned* __restrict__ bar)
{
    const int bg = blockIdx.x & 7, rg = blockIdx.x >> 3;
    const int tid = threadIdx.x;
    const int kq = tid & 3, rhalf = tid >> 2;
    const int u2 = tid >> 3, b2 = tid & 7;
    const int uglob = rg * DUP + u2;
    const int w = tid >> 6, lane = tid & 63;
    const size_t PSTR = (size_t)BATCH * PROJ;
    const size_t DPP  = (size_t)DRG * PSTR;

    __shared__ __align__(16) float inp0[DBP][120];
    __shared__ __align__(16) float h1b[DBP][52];
    __shared__ __align__(16) float h0n[DBP][52];
    __shared__ float xch[4][DUP][17];
    __shared__ float htl[DBP][68];
    __shared__ float wslT0[DUP][52];
    __shared__ float wslT1[DUP][52];

    for (int i = tid; i < PROJ * DUP; i += 512) {
        int p = i >> 6, uu = i & 63;
        wslT0[uu][p] = Whr0[(size_t)p * HID + rg * DUP + uu];
        wslT1[uu][p] = Whr1[(size_t)p * HID + rg * DUP + uu];
    }
    float bs0[4], bs1[4];
    #pragma unroll
    for (int gg = 0; gg < 4; ++gg) {
        bs0[gg] = bih0[gg * HID + uglob] + bhh0[gg * HID + uglob];
        bs1[gg] = bih1[gg * HID + uglob] + bhh1[gg * HID + uglob];
    }
    float c0[2], c1[2];
    #pragma unroll
    for (int hh = 0; hh < 2; ++hh) {
        int bglob = bg * DBP + b2 + 8 * hh;
        c0[hh] = cs[(size_t)bglob * HID + uglob];
        c1[hh] = cs[(size_t)(BATCH + bglob) * HID + uglob];
    }
    __syncthreads();

    unsigned* ctr = bar + bg * 64;
    unsigned phase = 0;

    for (int t = 0; t < FUT; ++t) {
        const float* ppaR = PPa + (size_t)((t - 1) & 1) * DPP;
        float*       ppaW = PPa + (size_t)(t & 1) * DPP;
        const float* ppbR = PPb + (size_t)((t - 1) & 1) * DPP;
        float*       ppbW = PPb + (size_t)(t & 1) * DPP;

        // ================= PHASE A =================
        if (t == 0) {
            for (int i = tid; i < DBP * PROJ; i += 512) {
                int b = i / PROJ, p = i % PROJ;
                int bglob = bg * DBP + b;
                inp0[b][p]      = hs[(size_t)bglob * PROJ + p];
                inp0[b][48 + p] = xin[(size_t)bglob * INF * SEQ + (size_t)p * SEQ + (SEQ - 1)];
                h1b[b][p]       = hs[(size_t)(BATCH + bglob) * PROJ + p];
            }
            if (tid < DBP * OUTF) {
                int b = tid >> 4, f = tid & 15;
                inp0[b][96 + f] = xdec[(size_t)(bg * DBP + b) * (OUTF * FUT) + (size_t)f * FUT];
            }
        } else {
            if (tid < 192) {
                int b = tid / 12, p = (tid % 12) * 4;
                int bglob = bg * DBP + b;
                f32x4 s = gsum8(ppaR + (size_t)bglob * PROJ + p, PSTR);
                *reinterpret_cast<f32x4*>(&inp0[b][p]) = s;
            } else if (tid < 384) {
                int idx = tid - 192;
                int b = idx / 12, p = (idx % 12) * 4;
                int bglob = bg * DBP + b;
                f32x4 s = gsum8(ppbR + (size_t)bglob * PROJ + p, PSTR);
                *reinterpret_cast<f32x4*>(&inp0[b][48 + p]) = s;
                *reinterpret_cast<f32x4*>(&h1b[b][p]) = s;
                if (rg == 0)
                    *reinterpret_cast<f32x4*>(&PRED[((size_t)(t - 1) * BATCH + bglob) * PROJ + p]) = s;
            } else {
                #pragma unroll
                for (int rep = 0; rep < 2; ++rep) {
                    int i2 = (tid - 384) + rep * 128;
                    int b = i2 >> 4, f = i2 & 15;
                    inp0[b][96 + f] = xdec[(size_t)(bg * DBP + b) * (OUTF * FUT) + (size_t)f * FUT + t];
                }
            }
        }
        __syncthreads();

        #pragma unroll
        for (int p = 0; p < 2; ++p) {
            int rid = p * 128 + rhalf;
            int g = rid >> 6, u = rid & 63;
            int grow = g * HID + rg * DUP + u;
            float wv[28];
            #pragma unroll
            for (int kk = 0; kk < 28; ++kk) {
                int k = kq * 28 + kk;
                wv[kk] = (k < 48) ? Whh0[(size_t)grow * 48 + k]
                                  : Wih0[(size_t)grow * 64 + (k - 48)];
            }
            float acc[DBP];
            #pragma unroll
            for (int b = 0; b < DBP; ++b) acc[b] = 0.f;
            const float* srcA = &inp0[0][0] + kq * 28;
            #pragma unroll
            for (int i4 = 0; i4 < 7; ++i4) {
                float w0 = wv[i4*4], w1 = wv[i4*4+1], w2 = wv[i4*4+2], w3 = wv[i4*4+3];
                #pragma unroll
                for (int b = 0; b < DBP; ++b) {
                    float4 xv = *reinterpret_cast<const float4*>(&srcA[b * 120 + i4 * 4]);
                    acc[b] += w0*xv.x + w1*xv.y + w2*xv.z + w3*xv.w;
                }
            }
            #pragma unroll
            for (int b = 0; b < DBP; ++b) {
                acc[b] += __shfl_xor(acc[b], 1, 64);
                acc[b] += __shfl_xor(acc[b], 2, 64);
            }
            if (kq == 0) {
                #pragma unroll
                for (int b = 0; b < DBP; ++b) xch[g][u][b] = acc[b];
            }
        }
        __syncthreads();
        #pragma unroll
        for (int hh = 0; hh < 2; ++hh) {
            int b = b2 + 8 * hh;
            float gi = xch[0][u2][b] + bs0[0];
            float gf = xch[1][u2][b] + bs0[1];
            float gc = xch[2][u2][b] + bs0[2];
            float go = xch[3][u2][b] + bs0[3];
            float si = fsigmoid(gi), sf = fsigmoid(gf), so = fsigmoid(go), tg = ftanh(gc);
            c0[hh] = sf * c0[hh] + si * tg;
            htl[b][u2] = so * ftanh(c0[hh]);
        }
        __syncthreads();
        if (lane < PROJ) {
            #pragma unroll
            for (int bb = 0; bb < 2; ++bb) {
                int b = 2 * w + bb;
                float s = 0.f;
                #pragma unroll
                for (int u4 = 0; u4 < 16; ++u4) {
                    float4 hv = *reinterpret_cast<const float4*>(&htl[b][u4 * 4]);
                    s += wslT0[u4*4+0][lane]*hv.x + wslT0[u4*4+1][lane]*hv.y
                       + wslT0[u4*4+2][lane]*hv.z + wslT0[u4*4+3][lane]*hv.w;
                }
                gstore(&ppaW[(size_t)rg * PSTR + (size_t)(bg * DBP + b) * PROJ + lane], s);
            }
        }
        phase += 1;
        bsync(ctr, phase * DRG, tid);

        // ================= PHASE B =================
        if (tid < 192) {
            int b = tid / 12, p = (tid % 12) * 4;
            f32x4 s = gsum8(ppaW + (size_t)(bg * DBP + b) * PROJ + p, PSTR);
            *reinterpret_cast<f32x4*>(&h0n[b][p]) = s;
        }
        __syncthreads();

        #pragma unroll
        for (int p = 0; p < 2; ++p) {
            int rid = p * 128 + rhalf;
            int g = rid >> 6, u = rid & 63;
            int grow = g * HID + rg * DUP + u;
            float wv[24];
            #pragma unroll
            for (int kk = 0; kk < 24; ++kk) {
                int k = kq * 24 + kk;
                wv[kk] = (k < 48) ? Whh1[(size_t)grow * 48 + k]
                                  : Wih1[(size_t)grow * 48 + (k - 48)];
            }
            const float* srcB = (kq < 2) ? (&h1b[0][0] + kq * 24)
                                         : (&h0n[0][0] + (kq - 2) * 24);
            float acc[DBP];
            #pragma unroll
            for (int b = 0; b < DBP; ++b) acc[b] = 0.f;
            #pragma unroll
            for (int i4 = 0; i4 < 6; ++i4) {
                float w0 = wv[i4*4], w1 = wv[i4*4+1], w2 = wv[i4*4+2], w3 = wv[i4*4+3];
                #pragma unroll
                for (int b = 0; b < DBP; ++b) {
                    float4 xv = *reinterpret_cast<const float4*>(&srcB[b * 52 + i4 * 4]);
                    acc[b] += w0*xv.x + w1*xv.y + w2*xv.z + w3*xv.w;
                }
            }
            #pragma unroll
            for (int b = 0; b < DBP; ++b) {
                acc[b] += __shfl_xor(acc[b], 1, 64);
                acc[b] += __shfl_xor(acc[b], 2, 64);
            }
            if (kq == 0) {
                #pragma unroll
                for (int b = 0; b < DBP; ++b) xch[g][u][b] = acc[b];
            }
        }
        __syncthreads();
        #pragma unroll
        for (int hh = 0; hh < 2; ++hh) {
            int b = b2 + 8 * hh;
            float gi = xch[0][u2][b] + bs1[0];
            float gf = xch[1][u2][b] + bs1[1];
            float gc = xch[2][u2][b] + bs1[2];
            float go = xch[3][u2][b] + bs1[3];
            float si = fsigmoid(gi), sf = fsigmoid(gf), so = fsigmoid(go), tg = ftanh(gc);
            c1[hh] = sf * c1[hh] + si * tg;
            htl[b][u2] = so * ftanh(c1[hh]);
        }
        __syncthreads();
        if (lane < PROJ) {
            #pragma unroll
            for (int bb = 0; bb < 2; ++bb) {
                int b = 2 * w + bb;
                float s = 0.f;
                #pragma unroll
                for (int u4 = 0; u4 < 16; ++u4) {
                    float4 hv = *reinterpret_cast<const float4*>(&htl[b][u4 * 4]);
                    s += wslT1[u4*4+0][lane]*hv.x + wslT1[u4*4+1][lane]*hv.y
                       + wslT1[u4*4+2][lane]*hv.z + wslT1[u4*4+3][lane]*hv.w;
                }
                gstore(&ppbW[(size_t)rg * PSTR + (size_t)(bg * DBP + b) * PROJ + lane], s);
            }
        }
        phase += 1;
        bsync(ctr, phase * DRG, tid);
    }

    if (tid < 2 * PROJ) {
        int bb = tid / PROJ, p = tid % PROJ;
        int bglob = bg * DBP + 2 * rg + bb;
        const float* ppbF = PPb + (size_t)((FUT - 1) & 1) * DPP;
        float s = 0.f;
        #pragma unroll
        for (int rr = 0; rr < DRG; ++rr)
            s += gload(&ppbF[(size_t)rr * PSTR + (size_t)bglob * PROJ + p]);
        PRED[((size_t)(FUT - 1) * BATCH + bglob) * PROJ + p] = s;
    }
}

// ---------------- basis contractions ----------------
__global__ void k_final(const float* __restrict__ theta, const float* __restrict__ H1,
                        const float* __restrict__ PRED, float* __restrict__ out)
{
    int b = blockIdx.x;
    __shared__ float th[2 * PROJ];
    if (threadIdx.x < 2 * PROJ) th[threadIdx.x] = theta[(size_t)b * 2 * PROJ + threadIdx.x];
    __syncthreads();
    for (int t = threadIdx.x; t < SEQ; t += 256) {
        float s = 0.f;
        #pragma unroll
        for (int p = 0; p < PROJ; ++p) s += th[PROJ + p] * H1[((size_t)t * BATCH + b) * PROJ + p];
        out[(size_t)b * SEQ + t] = s;
    }
    for (int t = threadIdx.x; t < FUT; t += 256) {
        float s = 0.f;
        #pragma unroll
        for (int p = 0; p < PROJ; ++p) s += th[p] * PRED[((size_t)t * BATCH + b) * PROJ + p];
        out[(size_t)BATCH * SEQ + (size_t)b * FUT + t] = s;
    }
}

extern "C" void kernel_launch(void* const* d_in, const int* in_sizes, int n_in,
                              void* d_out, int out_size, void* d_ws, size_t ws_size,
                              hipStream_t stream)
{
    (void)in_sizes; (void)n_in; (void)out_size; (void)ws_size;
    const float* theta = (const float*)d_in[0];
    const float* xin   = (const float*)d_in[1];
    const float* xdec  = (const float*)d_in[2];
    const float* eW0i = (const float*)d_in[3];
    const float* eW0h = (const float*)d_in[4];
    const float* eb0i = (const float*)d_in[5];
    const float* eb0h = (const float*)d_in[6];
    const float* eW0r = (const float*)d_in[7];
    const float* eW1i = (const float*)d_in[8];
    const float* eW1h = (const float*)d_in[9];
    const float* eb1i = (const float*)d_in[10];
    const float* eb1h = (const float*)d_in[11];
    const float* eW1r = (const float*)d_in[12];
    const float* dW0i = (const float*)d_in[13];
    const float* dW0h = (const float*)d_in[14];
    const float* db0i = (const float*)d_in[15];
    const float* db0h = (const float*)d_in[16];
    const float* dW0r = (const float*)d_in[17];
    const float* dW1i = (const float*)d_in[18];
    const float* dW1h = (const float*)d_in[19];
    const float* db1i = (const float*)d_in[20];
    const float* db1h = (const float*)d_in[21];
    const float* dW1r = (const float*)d_in[22];

    float* ws = (float*)d_ws;
    size_t off = 0;
    float* H0x  = ws + off; off += (size_t)SEQ * BATCH * PROJ;
    float* H1   = ws + off; off += (size_t)SEQ * BATCH * PROJ;
    float* PRED = ws + off; off += (size_t)FUT * BATCH * PROJ;
    float* hs   = ws + off; off += (size_t)2 * BATCH * PROJ;
    float* cs   = ws + off; off += (size_t)2 * BATCH * HID;
    float* WT0  = ws + off; off += (size_t)INF * G4;
    float* WT1  = ws + off; off += (size_t)PROJ * G4;
    const size_t DPP = (size_t)DRG * BATCH * PROJ;
    float* PPa  = ws + off; off += 2 * DPP;
    float* PPb  = ws + off; off += 2 * DPP;
    off = (off + 63) & ~(size_t)63;
    unsigned* eflags = (unsigned*)(ws + off); off += BATCH * 16;
    unsigned* bar    = (unsigned*)(ws + off); off += DBG * 64;

    hipMemsetAsync(eflags, 0, (BATCH * 16 + DBG * 64) * sizeof(unsigned), stream);
    k_wtrans<<<dim3(G4 / 32, 2), dim3(32, 8), 0, stream>>>(eW0i, WT0, G4, INF);
    k_wtrans<<<dim3(G4 / 32, 2), dim3(32, 8), 0, stream>>>(eW1i, WT1, G4, PROJ);
    k_enc<<<2 * BATCH, 512, 0, stream>>>(xin,
                                         WT0, eW0h, eb0i, eb0h, eW0r,
                                         WT1, eW1h, eb1i, eb1h, eW1r,
                                         H0x, H1, hs, cs, eflags);
    k_decP<<<DRG * DBG, 512, 0, stream>>>(xdec, dW0i, dW0h, db0i, db0h, dW0r,
                                          dW1i, dW1h, db1i, db1h, dW1r,
                                          hs, cs, xin, PPa, PPb, PRED, bar);
    k_final<<<BATCH, 256, 0, stream>>>(theta, H1, PRED, (float*)d_out);
}

// Round 17
// 5380.319 us; speedup vs baseline: 1.4003x; 1.0235x over previous
//
#include <hip/hip_runtime.h>
#include <cstdint>
#include <cstddef>

#define BATCH 128
#define INF   64
#define OUTF  16
#define SEQ   512
#define FUT   96
#define HID   512
#define G4    2048
#define PROJ  48
#define ECH   4

#define DRG 8
#define DBG 8
#define DUP 64
#define DBP 16

typedef float f32x4 __attribute__((ext_vector_type(4)));

__device__ __forceinline__ float fsigmoid(float x) {
    float e = __builtin_amdgcn_exp2f(-1.4426950408889634f * x);
    return __builtin_amdgcn_rcpf(1.0f + e);
}
__device__ __forceinline__ float ftanh(float x) {
    float e = __builtin_amdgcn_exp2f(2.8853900817779268f * x);
    return 1.0f - 2.0f * __builtin_amdgcn_rcpf(1.0f + e);
}

// LLC-coherent scalar ops (cross-WG traffic)
__device__ __forceinline__ float gload(const float* p) {
    return __hip_atomic_load(p, __ATOMIC_RELAXED, __HIP_MEMORY_SCOPE_AGENT);
}
__device__ __forceinline__ void gstore(float* p, float v) {
    __hip_atomic_store(p, v, __ATOMIC_RELAXED, __HIP_MEMORY_SCOPE_AGENT);
}

// coherent vector gather: sum of 8 partials at p + rr*stride, fixed tree order.
__device__ __forceinline__ f32x4 gsum8(const float* p, size_t stride) {
    f32x4 a0, a1, a2, a3, a4, a5, a6, a7;
    asm volatile(
        "global_load_dwordx4 %0, %8, off sc0 sc1\n\t"
        "global_load_dwordx4 %1, %9, off sc0 sc1\n\t"
        "global_load_dwordx4 %2, %10, off sc0 sc1\n\t"
        "global_load_dwordx4 %3, %11, off sc0 sc1\n\t"
        "global_load_dwordx4 %4, %12, off sc0 sc1\n\t"
        "global_load_dwordx4 %5, %13, off sc0 sc1\n\t"
        "global_load_dwordx4 %6, %14, off sc0 sc1\n\t"
        "global_load_dwordx4 %7, %15, off sc0 sc1\n\t"
        "s_waitcnt vmcnt(0)"
        : "=&v"(a0), "=&v"(a1), "=&v"(a2), "=&v"(a3),
          "=&v"(a4), "=&v"(a5), "=&v"(a6), "=&v"(a7)
        : "v"(p), "v"(p + stride), "v"(p + 2 * stride), "v"(p + 3 * stride),
          "v"(p + 4 * stride), "v"(p + 5 * stride), "v"(p + 6 * stride),
          "v"(p + 7 * stride)
        : "memory");
    return ((a0 + a1) + (a2 + a3)) + ((a4 + a5) + (a6 + a7));
}

// chain barrier among DRG WGs: counter add by tid0, poll with backoff.
__device__ __forceinline__ void bsync(unsigned* ctr, unsigned target, int tid) {
    asm volatile("s_waitcnt vmcnt(0)" ::: "memory");
    __syncthreads();
    if (tid == 0) {
        __hip_atomic_fetch_add(ctr, 1u, __ATOMIC_RELAXED, __HIP_MEMORY_SCOPE_AGENT);
        while (__hip_atomic_load(ctr, __ATOMIC_RELAXED, __HIP_MEMORY_SCOPE_AGENT) < target)
            __builtin_amdgcn_s_sleep(2);
    }
    __syncthreads();
    asm volatile("" ::: "memory");
}

// ---------------- guarded transpose W[R][C] -> WT[C][R] ----------------
__global__ void k_wtrans(const float* __restrict__ W, float* __restrict__ WT,
                         int R, int C) {
    __shared__ float tile[32][33];
    int r0 = blockIdx.x * 32, c0 = blockIdx.y * 32;
    int tx = threadIdx.x, ty = threadIdx.y;
    #pragma unroll
    for (int i = 0; i < 4; ++i) {
        int r = r0 + ty + 8 * i;
        if (r < R && c0 + tx < C) tile[ty + 8 * i][tx] = W[(size_t)r * C + c0 + tx];
    }
    __syncthreads();
    #pragma unroll
    for (int i = 0; i < 4; ++i) {
        int c = c0 + ty + 8 * i;
        if (c < C && r0 + tx < R) WT[(size_t)c * R + r0 + tx] = tile[tx][ty + 8 * i];
    }
}

// ---------------- persistent fused encoder: 1024 thr, gate-split halves ----------------
// threads [0,512): I,F gates of unit j + c/ht/proj; [512,1024): G,O gates -> LDS.
// Same L2 weight volume, half per-thread work, 2x waves (16/CU) for latency hiding.
__global__ __launch_bounds__(1024) void k_enc(
    const float* __restrict__ x,
    const float* __restrict__ WT0, const float* __restrict__ Whh0,
    const float* __restrict__ bih0, const float* __restrict__ bhh0,
    const float* __restrict__ Whr0,
    const float* __restrict__ WT1, const float* __restrict__ Whh1,
    const float* __restrict__ bih1, const float* __restrict__ bhh1,
    const float* __restrict__ Whr1,
    float* __restrict__ H0x, float* __restrict__ H1,
    float* __restrict__ hs, float* __restrict__ cs,
    unsigned* __restrict__ eflags)
{
    const bool L1w = blockIdx.x >= BATCH;
    const int b = L1w ? blockIdx.x - BATCH : blockIdx.x;
    const int tid = threadIdx.x;
    const int j = tid & 511;
    const int half = tid >> 9;          // 0: I,F   1: G,O
    const int wave = tid >> 6, lane = tid & 63;   // 16 waves
    const float* WT  = L1w ? WT1 : WT0;
    const float* Whh = L1w ? Whh1 : Whh0;
    const float* Whr = L1w ? Whr1 : Whr0;
    const float* bih = L1w ? bih1 : bih0;
    const float* bhh = L1w ? bhh1 : bhh0;
    const int K = L1w ? PROJ : INF;

    __shared__ float whr[PROJ][HID + 4];
    __shared__ __align__(16) float xs[ECH][INF + 4];
    __shared__ __align__(16) float ht_lds[HID];
    __shared__ __align__(16) float h_cur[PROJ];
    __shared__ __align__(16) float gG[HID];
    __shared__ __align__(16) float gO[HID];

    const int row0 = half ? (j + 2 * HID) : j;          // I or G
    const int row1 = half ? (j + 3 * HID) : (j + HID);  // F or O

    // 2 Whh rows per thread (96 floats; remat-streamed like R14)
    float wA[PROJ], wB[PROJ];
    #pragma unroll
    for (int k4 = 0; k4 < 12; ++k4) {
        float4 va = *reinterpret_cast<const float4*>(&Whh[(size_t)row0 * PROJ + 4 * k4]);
        float4 vb = *reinterpret_cast<const float4*>(&Whh[(size_t)row1 * PROJ + 4 * k4]);
        wA[4*k4+0]=va.x; wA[4*k4+1]=va.y; wA[4*k4+2]=va.z; wA[4*k4+3]=va.w;
        wB[4*k4+0]=vb.x; wB[4*k4+1]=vb.y; wB[4*k4+2]=vb.z; wB[4*k4+3]=vb.w;
    }
    for (int idx = tid; idx < PROJ * HID; idx += 1024) {
        int p = idx >> 9, jj = idx & 511;
        whr[p][jj] = Whr[(size_t)p * HID + jj];
    }
    float bA = bih[row0] + bhh[row0];
    float bB = bih[row1] + bhh[row1];
    float c = 0.f;
    if (tid < PROJ) h_cur[tid] = 0.f;
    __syncthreads();

    for (int t0 = 0; t0 < SEQ; t0 += ECH) {
        // ---- stage chunk inputs ----
        if (!L1w) {
            if (tid < INF * ECH) {
                int k = tid >> 2, dt = tid & 3;
                xs[dt][k] = x[(size_t)b * INF * SEQ + (size_t)k * SEQ + t0 + dt];
            }
        } else {
            if (tid == 0) {
                unsigned need = (unsigned)(t0 / ECH) + 1;
                while (__hip_atomic_load(&eflags[b * 16], __ATOMIC_RELAXED,
                                         __HIP_MEMORY_SCOPE_AGENT) < need)
                    __builtin_amdgcn_s_sleep(2);
            }
            __syncthreads();
            asm volatile("" ::: "memory");
            if (tid < PROJ * ECH) {
                int dt = tid / PROJ, p = tid % PROJ;
                xs[dt][p] = gload(&H0x[((size_t)(t0 + dt) * BATCH + b) * PROJ + p]);
            }
        }
        __syncthreads();

        // ---- input-gate GEMM: 2 gates per thread (split like R14) ----
        float aA[ECH], aB[ECH];
        #pragma unroll
        for (int dt = 0; dt < ECH; ++dt) { aA[dt] = bA; aB[dt] = bB; }
        for (int kq = 0; kq < K / 4; ++kq) {
            float wa0 = WT[(size_t)(kq*4+0) * G4 + row0];
            float wa1 = WT[(size_t)(kq*4+1) * G4 + row0];
            float wa2 = WT[(size_t)(kq*4+2) * G4 + row0];
            float wa3 = WT[(size_t)(kq*4+3) * G4 + row0];
            float wb0 = WT[(size_t)(kq*4+0) * G4 + row1];
            float wb1 = WT[(size_t)(kq*4+1) * G4 + row1];
            float wb2 = WT[(size_t)(kq*4+2) * G4 + row1];
            float wb3 = WT[(size_t)(kq*4+3) * G4 + row1];
            #pragma unroll
            for (int dt = 0; dt < ECH; ++dt) {
                float4 xv = *reinterpret_cast<const float4*>(&xs[dt][kq * 4]);
                aA[dt] += wa0*xv.x + wa1*xv.y + wa2*xv.z + wa3*xv.w;
                aB[dt] += wb0*xv.x + wb1*xv.y + wb2*xv.z + wb3*xv.w;
            }
        }

        // ---- recurrent steps ----
        #pragma unroll
        for (int dt = 0; dt < ECH; ++dt) {
            float sA = aA[dt], sB = aB[dt];
            #pragma unroll
            for (int k4 = 0; k4 < 12; ++k4) {
                float4 h4 = *reinterpret_cast<const float4*>(&h_cur[4 * k4]);
                sA += wA[4*k4+0]*h4.x + wA[4*k4+1]*h4.y + wA[4*k4+2]*h4.z + wA[4*k4+3]*h4.w;
                sB += wB[4*k4+0]*h4.x + wB[4*k4+1]*h4.y + wB[4*k4+2]*h4.z + wB[4*k4+3]*h4.w;
            }
            if (half) { gG[j] = sA; gO[j] = sB; }
            __syncthreads();
            if (!half) {
                float si = fsigmoid(sA), sf = fsigmoid(sB);
                float tg = ftanh(gG[j]), so = fsigmoid(gO[j]);
                c = sf * c + si * tg;
                ht_lds[j] = so * ftanh(c);
            }
            __syncthreads();
            // proj: 16 waves x 3 outputs
            float rq[3];
            #pragma unroll
            for (int q = 0; q < 3; ++q) {
                int p = wave * 3 + q;
                float s = 0.f;
                #pragma unroll
                for (int m = 0; m < 8; ++m)
                    s += whr[p][lane + 64 * m] * ht_lds[lane + 64 * m];
                #pragma unroll
                for (int o = 32; o; o >>= 1) s += __shfl_xor(s, o, 64);
                rq[q] = s;
            }
            if (lane == 0) {
                int t = t0 + dt;
                #pragma unroll
                for (int q = 0; q < 3; ++q) {
                    int p = wave * 3 + q;
                    float v = rq[q];
                    h_cur[p] = v;
                    if (!L1w) gstore(&H0x[((size_t)t * BATCH + b) * PROJ + p], v);
                    else      H1[((size_t)t * BATCH + b) * PROJ + p] = v;
                }
            }
            __syncthreads();
        }
        if (!L1w) {
            asm volatile("s_waitcnt vmcnt(0)" ::: "memory");
            __syncthreads();
            if (tid == 0)
                __hip_atomic_store(&eflags[b * 16], (unsigned)(t0 / ECH) + 1,
                                   __ATOMIC_RELAXED, __HIP_MEMORY_SCOPE_AGENT);
        }
    }
    if (!half) cs[((size_t)(L1w ? BATCH : 0) + b) * HID + j] = c;
    if (tid < PROJ) hs[((size_t)(L1w ? BATCH : 0) + b) * PROJ + tid] = h_cur[tid];
}

// ---------------- persistent spill-free decoder: 64 WGs, 2 syncs/step ----------------
__global__ __launch_bounds__(512) void k_decP(
    const float* __restrict__ xdec,
    const float* __restrict__ Wih0, const float* __restrict__ Whh0,
    const float* __restrict__ bih0, const float* __restrict__ bhh0,
    const float* __restrict__ Whr0,
    const float* __restrict__ Wih1, const float* __restrict__ Whh1,
    const float* __restrict__ bih1, const float* __restrict__ bhh1,
    const float* __restrict__ Whr1,
    const float* __restrict__ hs, const float* __restrict__ cs,
    const float* __restrict__ xin,
    float* __restrict__ PPa, float* __restrict__ PPb,
    float* __restrict__ PRED,
    unsigned* __restrict__ bar)
{
    const int bg = blockIdx.x & 7, rg = blockIdx.x >> 3;
    const int tid = threadIdx.x;
    const int kq = tid & 3, rhalf = tid >> 2;
    const int u2 = tid >> 3, b2 = tid & 7;
    const int uglob = rg * DUP + u2;
    const int w = tid >> 6, lane = tid & 63;
    const size_t PSTR = (size_t)BATCH * PROJ;
    const size_t DPP  = (size_t)DRG * PSTR;

    __shared__ __align__(16) float inp0[DBP][120];
    __shared__ __align__(16) float h1b[DBP][52];
    __shared__ __align__(16) float h0n[DBP][52];
    __shared__ float xch[4][DUP][17];
    __shared__ float htl[DBP][68];
    __shared__ float wslT0[DUP][52];
    __shared__ float wslT1[DUP][52];

    for (int i = tid; i < PROJ * DUP; i += 512) {
        int p = i >> 6, uu = i & 63;
        wslT0[uu][p] = Whr0[(size_t)p * HID + rg * DUP + uu];
        wslT1[uu][p] = Whr1[(size_t)p * HID + rg * DUP + uu];
    }
    float bs0[4], bs1[4];
    #pragma unroll
    for (int gg = 0; gg < 4; ++gg) {
        bs0[gg] = bih0[gg * HID + uglob] + bhh0[gg * HID + uglob];
        bs1[gg] = bih1[gg * HID + uglob] + bhh1[gg * HID + uglob];
    }
    float c0[2], c1[2];
    #pragma unroll
    for (int hh = 0; hh < 2; ++hh) {
        int bglob = bg * DBP + b2 + 8 * hh;
        c0[hh] = cs[(size_t)bglob * HID + uglob];
        c1[hh] = cs[(size_t)(BATCH + bglob) * HID + uglob];
    }
    __syncthreads();

    unsigned* ctr = bar + bg * 64;
    unsigned phase = 0;

    for (int t = 0; t < FUT; ++t) {
        const float* ppaR = PPa + (size_t)((t - 1) & 1) * DPP;
        float*       ppaW = PPa + (size_t)(t & 1) * DPP;
        const float* ppbR = PPb + (size_t)((t - 1) & 1) * DPP;
        float*       ppbW = PPb + (size_t)(t & 1) * DPP;

        // ================= PHASE A =================
        if (t == 0) {
            for (int i = tid; i < DBP * PROJ; i += 512) {
                int b = i / PROJ, p = i % PROJ;
                int bglob = bg * DBP + b;
                inp0[b][p]      = hs[(size_t)bglob * PROJ + p];
                inp0[b][48 + p] = xin[(size_t)bglob * INF * SEQ + (size_t)p * SEQ + (SEQ - 1)];
                h1b[b][p]       = hs[(size_t)(BATCH + bglob) * PROJ + p];
            }
            if (tid < DBP * OUTF) {
                int b = tid >> 4, f = tid & 15;
                inp0[b][96 + f] = xdec[(size_t)(bg * DBP + b) * (OUTF * FUT) + (size_t)f * FUT];
            }
        } else {
            if (tid < 192) {
                int b = tid / 12, p = (tid % 12) * 4;
                int bglob = bg * DBP + b;
                f32x4 s = gsum8(ppaR + (size_t)bglob * PROJ + p, PSTR);
                *reinterpret_cast<f32x4*>(&inp0[b][p]) = s;
            } else if (tid < 384) {
                int idx = tid - 192;
                int b = idx / 12, p = (idx % 12) * 4;
                int bglob = bg * DBP + b;
                f32x4 s = gsum8(ppbR + (size_t)bglob * PROJ + p, PSTR);
                *reinterpret_cast<f32x4*>(&inp0[b][48 + p]) = s;
                *reinterpret_cast<f32x4*>(&h1b[b][p]) = s;
                if (rg == 0)
                    *reinterpret_cast<f32x4*>(&PRED[((size_t)(t - 1) * BATCH + bglob) * PROJ + p]) = s;
            } else {
                #pragma unroll
                for (int rep = 0; rep < 2; ++rep) {
                    int i2 = (tid - 384) + rep * 128;
                    int b = i2 >> 4, f = i2 & 15;
                    inp0[b][96 + f] = xdec[(size_t)(bg * DBP + b) * (OUTF * FUT) + (size_t)f * FUT + t];
                }
            }
        }
        __syncthreads();

        #pragma unroll
        for (int p = 0; p < 2; ++p) {
            int rid = p * 128 + rhalf;
            int g = rid >> 6, u = rid & 63;
            int grow = g * HID + rg * DUP + u;
            float wv[28];
            #pragma unroll
            for (int kk = 0; kk < 28; ++kk) {
                int k = kq * 28 + kk;
                wv[kk] = (k < 48) ? Whh0[(size_t)grow * 48 + k]
                                  : Wih0[(size_t)grow * 64 + (k - 48)];
            }
            float acc[DBP];
            #pragma unroll
            for (int b = 0; b < DBP; ++b) acc[b] = 0.f;
            const float* srcA = &inp0[0][0] + kq * 28;
            #pragma unroll
            for (int i4 = 0; i4 < 7; ++i4) {
                float w0 = wv[i4*4], w1 = wv[i4*4+1], w2 = wv[i4*4+2], w3 = wv[i4*4+3];
                #pragma unroll
                for (int b = 0; b < DBP; ++b) {
                    float4 xv = *reinterpret_cast<const float4*>(&srcA[b * 120 + i4 * 4]);
                    acc[b] += w0*xv.x + w1*xv.y + w2*xv.z + w3*xv.w;
                }
            }
            #pragma unroll
            for (int b = 0; b < DBP; ++b) {
                acc[b] += __shfl_xor(acc[b], 1, 64);
                acc[b] += __shfl_xor(acc[b], 2, 64);
            }
            if (kq == 0) {
                #pragma unroll
                for (int b = 0; b < DBP; ++b) xch[g][u][b] = acc[b];
            }
        }
        __syncthreads();
        #pragma unroll
        for (int hh = 0; hh < 2; ++hh) {
            int b = b2 + 8 * hh;
            float gi = xch[0][u2][b] + bs0[0];
            float gf = xch[1][u2][b] + bs0[1];
            float gc = xch[2][u2][b] + bs0[2];
            float go = xch[3][u2][b] + bs0[3];
            float si = fsigmoid(gi), sf = fsigmoid(gf), so = fsigmoid(go), tg = ftanh(gc);
            c0[hh] = sf * c0[hh] + si * tg;
            htl[b][u2] = so * ftanh(c0[hh]);
        }
        __syncthreads();
        if (lane < PROJ) {
            #pragma unroll
            for (int bb = 0; bb < 2; ++bb) {
                int b = 2 * w + bb;
                float s = 0.f;
                #pragma unroll
                for (int u4 = 0; u4 < 16; ++u4) {
                    float4 hv = *reinterpret_cast<const float4*>(&htl[b][u4 * 4]);
                    s += wslT0[u4*4+0][lane]*hv.x + wslT0[u4*4+1][lane]*hv.y
                       + wslT0[u4*4+2][lane]*hv.z + wslT0[u4*4+3][lane]*hv.w;
                }
                gstore(&ppaW[(size_t)rg * PSTR + (size_t)(bg * DBP + b) * PROJ + lane], s);
            }
        }
        phase += 1;
        bsync(ctr, phase * DRG, tid);

        // ================= PHASE B =================
        if (tid < 192) {
            int b = tid / 12, p = (tid % 12) * 4;
            f32x4 s = gsum8(ppaW + (size_t)(bg * DBP + b) * PROJ + p, PSTR);
            *reinterpret_cast<f32x4*>(&h0n[b][p]) = s;
        }
        __syncthreads();

        #pragma unroll
        for (int p = 0; p < 2; ++p) {
            int rid = p * 128 + rhalf;
            int g = rid >> 6, u = rid & 63;
            int grow = g * HID + rg * DUP + u;
            float wv[24];
            #pragma unroll
            for (int kk = 0; kk < 24; ++kk) {
                int k = kq * 24 + kk;
                wv[kk] = (k < 48) ? Whh1[(size_t)grow * 48 + k]
                                  : Wih1[(size_t)grow * 48 + (k - 48)];
            }
            const float* srcB = (kq < 2) ? (&h1b[0][0] + kq * 24)
                                         : (&h0n[0][0] + (kq - 2) * 24);
            float acc[DBP];
            #pragma unroll
            for (int b = 0; b < DBP; ++b) acc[b] = 0.f;
            #pragma unroll
            for (int i4 = 0; i4 < 6; ++i4) {
                float w0 = wv[i4*4], w1 = wv[i4*4+1], w2 = wv[i4*4+2], w3 = wv[i4*4+3];
                #pragma unroll
                for (int b = 0; b < DBP; ++b) {
                    float4 xv = *reinterpret_cast<const float4*>(&srcB[b * 52 + i4 * 4]);
                    acc[b] += w0*xv.x + w1*xv.y + w2*xv.z + w3*xv.w;
                }
            }
            #pragma unroll
            for (int b = 0; b < DBP; ++b) {
                acc[b] += __shfl_xor(acc[b], 1, 64);
                acc[b] += __shfl_xor(acc[b], 2, 64);
            }
            if (kq == 0) {
                #pragma unroll
                for (int b = 0; b < DBP; ++b) xch[g][u][b] = acc[b];
            }
        }
        __syncthreads();
        #pragma unroll
        for (int hh = 0; hh < 2; ++hh) {
            int b = b2 + 8 * hh;
            float gi = xch[0][u2][b] + bs1[0];
            float gf = xch[1][u2][b] + bs1[1];
            float gc = xch[2][u2][b] + bs1[2];
            float go = xch[3][u2][b] + bs1[3];
            float si = fsigmoid(gi), sf = fsigmoid(gf), so = fsigmoid(go), tg = ftanh(gc);
            c1[hh] = sf * c1[hh] + si * tg;
            htl[b][u2] = so * ftanh(c1[hh]);
        }
        __syncthreads();
        if (lane < PROJ) {
            #pragma unroll
            for (int bb = 0; bb < 2; ++bb) {
                int b = 2 * w + bb;
                float s = 0.f;
                #pragma unroll
                for (int u4 = 0; u4 < 16; ++u4) {
                    float4 hv = *reinterpret_cast<const float4*>(&htl[b][u4 * 4]);
                    s += wslT1[u4*4+0][lane]*hv.x + wslT1[u4*4+1][lane]*hv.y
                       + wslT1[u4*4+2][lane]*hv.z + wslT1[u4*4+3][lane]*hv.w;
                }
                gstore(&ppbW[(size_t)rg * PSTR + (size_t)(bg * DBP + b) * PROJ + lane], s);
            }
        }
        phase += 1;
        bsync(ctr, phase * DRG, tid);
    }

    if (tid < 2 * PROJ) {
        int bb = tid / PROJ, p = tid % PROJ;
        int bglob = bg * DBP + 2 * rg + bb;
        const float* ppbF = PPb + (size_t)((FUT - 1) & 1) * DPP;
        float s = 0.f;
        #pragma unroll
        for (int rr = 0; rr < DRG; ++rr)
            s += gload(&ppbF[(size_t)rr * PSTR + (size_t)bglob * PROJ + p]);
        PRED[((size_t)(FUT - 1) * BATCH + bglob) * PROJ + p] = s;
    }
}

// ---------------- basis contractions ----------------
__global__ void k_final(const float* __restrict__ theta, const float* __restrict__ H1,
                        const float* __restrict__ PRED, float* __restrict__ out)
{
    int b = blockIdx.x;
    __shared__ float th[2 * PROJ];
    if (threadIdx.x < 2 * PROJ) th[threadIdx.x] = theta[(size_t)b * 2 * PROJ + threadIdx.x];
    __syncthreads();
    for (int t = threadIdx.x; t < SEQ; t += 256) {
        float s = 0.f;
        #pragma unroll
        for (int p = 0; p < PROJ; ++p) s += th[PROJ + p] * H1[((size_t)t * BATCH + b) * PROJ + p];
        out[(size_t)b * SEQ + t] = s;
    }
    for (int t = threadIdx.x; t < FUT; t += 256) {
        float s = 0.f;
        #pragma unroll
        for (int p = 0; p < PROJ; ++p) s += th[p] * PRED[((size_t)t * BATCH + b) * PROJ + p];
        out[(size_t)BATCH * SEQ + (size_t)b * FUT + t] = s;
    }
}

extern "C" void kernel_launch(void* const* d_in, const int* in_sizes, int n_in,
                              void* d_out, int out_size, void* d_ws, size_t ws_size,
                              hipStream_t stream)
{
    (void)in_sizes; (void)n_in; (void)out_size; (void)ws_size;
    const float* theta = (const float*)d_in[0];
    const float* xin   = (const float*)d_in[1];
    const float* xdec  = (const float*)d_in[2];
    const float* eW0i = (const float*)d_in[3];
    const float* eW0h = (const float*)d_in[4];
    const float* eb0i = (const float*)d_in[5];
    const float* eb0h = (const float*)d_in[6];
    const float* eW0r = (const float*)d_in[7];
    const float* eW1i = (const float*)d_in[8];
    const float* eW1h = (const float*)d_in[9];
    const float* eb1i = (const float*)d_in[10];
    const float* eb1h = (const float*)d_in[11];
    const float* eW1r = (const float*)d_in[12];
    const float* dW0i = (const float*)d_in[13];
    const float* dW0h = (const float*)d_in[14];
    const float* db0i = (const float*)d_in[15];
    const float* db0h = (const float*)d_in[16];
    const float* dW0r = (const float*)d_in[17];
    const float* dW1i = (const float*)d_in[18];
    const float* dW1h = (const float*)d_in[19];
    const float* db1i = (const float*)d_in[20];
    const float* db1h = (const float*)d_in[21];
    const float* dW1r = (const float*)d_in[22];

    float* ws = (float*)d_ws;
    size_t off = 0;
    float* H0x  = ws + off; off += (size_t)SEQ * BATCH * PROJ;
    float* H1   = ws + off; off += (size_t)SEQ * BATCH * PROJ;
    float* PRED = ws + off; off += (size_t)FUT * BATCH * PROJ;
    float* hs   = ws + off; off += (size_t)2 * BATCH * PROJ;
    float* cs   = ws + off; off += (size_t)2 * BATCH * HID;
    float* WT0  = ws + off; off += (size_t)INF * G4;
    float* WT1  = ws + off; off += (size_t)PROJ * G4;
    const size_t DPP = (size_t)DRG * BATCH * PROJ;
    float* PPa  = ws + off; off += 2 * DPP;
    float* PPb  = ws + off; off += 2 * DPP;
    off = (off + 63) & ~(size_t)63;
    unsigned* eflags = (unsigned*)(ws + off); off += BATCH * 16;
    unsigned* bar    = (unsigned*)(ws + off); off += DBG * 64;

    hipMemsetAsync(eflags, 0, (BATCH * 16 + DBG * 64) * sizeof(unsigned), stream);
    k_wtrans<<<dim3(G4 / 32, 2), dim3(32, 8), 0, stream>>>(eW0i, WT0, G4, INF);
    k_wtrans<<<dim3(G4 / 32, 2), dim3(32, 8), 0, stream>>>(eW1i, WT1, G4, PROJ);
    k_enc<<<2 * BATCH, 1024, 0, stream>>>(xin,
                                          WT0, eW0h, eb0i, eb0h, eW0r,
                                          WT1, eW1h, eb1i, eb1h, eW1r,
                                          H0x, H1, hs, cs, eflags);
    k_decP<<<DRG * DBG, 512, 0, stream>>>(xdec, dW0i, dW0h, db0i, db0h, dW0r,
                                          dW1i, dW1h, db1i, db1h, dW1r,
                                          hs, cs, xin, PPa, PPb, PRED, bar);
    k_final<<<BATCH, 256, 0, stream>>>(theta, H1, PRED, (float*)d_out);
}

// Round 18
// 5001.168 us; speedup vs baseline: 1.5065x; 1.0758x over previous
//
#include <hip/hip_runtime.h>
#include <cstdint>
#include <cstddef>

#define BATCH 128
#define INF   64
#define OUTF  16
#define SEQ   512
#define FUT   96
#define HID   512
#define G4    2048
#define PROJ  48
#define ECH   4

#define DRG 8
#define DBG 8
#define DUP 64
#define DBP 16

typedef float f32x4 __attribute__((ext_vector_type(4)));

__device__ __forceinline__ float fsigmoid(float x) {
    float e = __builtin_amdgcn_exp2f(-1.4426950408889634f * x);
    return __builtin_amdgcn_rcpf(1.0f + e);
}
__device__ __forceinline__ float ftanh(float x) {
    float e = __builtin_amdgcn_exp2f(2.8853900817779268f * x);
    return 1.0f - 2.0f * __builtin_amdgcn_rcpf(1.0f + e);
}

// LLC-coherent scalar ops (cross-WG traffic)
__device__ __forceinline__ float gload(const float* p) {
    return __hip_atomic_load(p, __ATOMIC_RELAXED, __HIP_MEMORY_SCOPE_AGENT);
}
__device__ __forceinline__ void gstore(float* p, float v) {
    __hip_atomic_store(p, v, __ATOMIC_RELAXED, __HIP_MEMORY_SCOPE_AGENT);
}

// coherent vector gather: sum of 8 partials at p + rr*stride, fixed tree order.
__device__ __forceinline__ f32x4 gsum8(const float* p, size_t stride) {
    f32x4 a0, a1, a2, a3, a4, a5, a6, a7;
    asm volatile(
        "global_load_dwordx4 %0, %8, off sc0 sc1\n\t"
        "global_load_dwordx4 %1, %9, off sc0 sc1\n\t"
        "global_load_dwordx4 %2, %10, off sc0 sc1\n\t"
        "global_load_dwordx4 %3, %11, off sc0 sc1\n\t"
        "global_load_dwordx4 %4, %12, off sc0 sc1\n\t"
        "global_load_dwordx4 %5, %13, off sc0 sc1\n\t"
        "global_load_dwordx4 %6, %14, off sc0 sc1\n\t"
        "global_load_dwordx4 %7, %15, off sc0 sc1\n\t"
        "s_waitcnt vmcnt(0)"
        : "=&v"(a0), "=&v"(a1), "=&v"(a2), "=&v"(a3),
          "=&v"(a4), "=&v"(a5), "=&v"(a6), "=&v"(a7)
        : "v"(p), "v"(p + stride), "v"(p + 2 * stride), "v"(p + 3 * stride),
          "v"(p + 4 * stride), "v"(p + 5 * stride), "v"(p + 6 * stride),
          "v"(p + 7 * stride)
        : "memory");
    return ((a0 + a1) + (a2 + a3)) + ((a4 + a5) + (a6 + a7));
}

// chain barrier among DRG WGs: counter add by tid0, poll with backoff.
__device__ __forceinline__ void bsync(unsigned* ctr, unsigned target, int tid) {
    asm volatile("s_waitcnt vmcnt(0)" ::: "memory");
    __syncthreads();
    if (tid == 0) {
        __hip_atomic_fetch_add(ctr, 1u, __ATOMIC_RELAXED, __HIP_MEMORY_SCOPE_AGENT);
        while (__hip_atomic_load(ctr, __ATOMIC_RELAXED, __HIP_MEMORY_SCOPE_AGENT) < target)
            __builtin_amdgcn_s_sleep(2);
    }
    __syncthreads();
    asm volatile("" ::: "memory");
}

// ---------------- guarded transpose W[R][C] -> WT[C][R] ----------------
__global__ void k_wtrans(const float* __restrict__ W, float* __restrict__ WT,
                         int R, int C) {
    __shared__ float tile[32][33];
    int r0 = blockIdx.x * 32, c0 = blockIdx.y * 32;
    int tx = threadIdx.x, ty = threadIdx.y;
    #pragma unroll
    for (int i = 0; i < 4; ++i) {
        int r = r0 + ty + 8 * i;
        if (r < R && c0 + tx < C) tile[ty + 8 * i][tx] = W[(size_t)r * C + c0 + tx];
    }
    __syncthreads();
    #pragma unroll
    for (int i = 0; i < 4; ++i) {
        int c = c0 + ty + 8 * i;
        if (c < C && r0 + tx < R) WT[(size_t)c * R + r0 + tx] = tile[tx][ty + 8 * i];
    }
}

// ---------------- persistent fused encoder (R14-exact: 512 thr, split GEMM) ----------------
__global__ __launch_bounds__(512) void k_enc(
    const float* __restrict__ x,
    const float* __restrict__ WT0, const float* __restrict__ Whh0,
    const float* __restrict__ bih0, const float* __restrict__ bhh0,
    const float* __restrict__ Whr0,
    const float* __restrict__ WT1, const float* __restrict__ Whh1,
    const float* __restrict__ bih1, const float* __restrict__ bhh1,
    const float* __restrict__ Whr1,
    float* __restrict__ H0x, float* __restrict__ H1,
    float* __restrict__ hs, float* __restrict__ cs,
    unsigned* __restrict__ eflags)
{
    const bool L1w = blockIdx.x >= BATCH;
    const int b = L1w ? blockIdx.x - BATCH : blockIdx.x;
    const int j = threadIdx.x;
    const int wave = j >> 6, lane = j & 63;
    const float* WT  = L1w ? WT1 : WT0;
    const float* Whh = L1w ? Whh1 : Whh0;
    const float* Whr = L1w ? Whr1 : Whr0;
    const float* bih = L1w ? bih1 : bih0;
    const float* bhh = L1w ? bhh1 : bhh0;
    const int K = L1w ? PROJ : INF;

    __shared__ float whr[PROJ][HID + 4];
    __shared__ __align__(16) float xs[ECH][INF + 4];
    __shared__ __align__(16) float ht_lds[HID];
    __shared__ __align__(16) float h_cur[PROJ];

    float wI[PROJ], wF[PROJ], wG[PROJ], wO[PROJ];
    #pragma unroll
    for (int k4 = 0; k4 < 12; ++k4) {
        float4 vi = *reinterpret_cast<const float4*>(&Whh[(size_t)j * PROJ + 4 * k4]);
        float4 vf = *reinterpret_cast<const float4*>(&Whh[(size_t)(j + HID) * PROJ + 4 * k4]);
        float4 vg = *reinterpret_cast<const float4*>(&Whh[(size_t)(j + 2 * HID) * PROJ + 4 * k4]);
        float4 vo = *reinterpret_cast<const float4*>(&Whh[(size_t)(j + 3 * HID) * PROJ + 4 * k4]);
        wI[4*k4+0]=vi.x; wI[4*k4+1]=vi.y; wI[4*k4+2]=vi.z; wI[4*k4+3]=vi.w;
        wF[4*k4+0]=vf.x; wF[4*k4+1]=vf.y; wF[4*k4+2]=vf.z; wF[4*k4+3]=vf.w;
        wG[4*k4+0]=vg.x; wG[4*k4+1]=vg.y; wG[4*k4+2]=vg.z; wG[4*k4+3]=vg.w;
        wO[4*k4+0]=vo.x; wO[4*k4+1]=vo.y; wO[4*k4+2]=vo.z; wO[4*k4+3]=vo.w;
    }
    for (int idx = j; idx < PROJ * HID; idx += 512) {
        int p = idx >> 9, jj = idx & 511;
        whr[p][jj] = Whr[(size_t)p * HID + jj];
    }
    float bI = bih[j] + bhh[j];
    float bF = bih[j + HID] + bhh[j + HID];
    float bG = bih[j + 2 * HID] + bhh[j + 2 * HID];
    float bO = bih[j + 3 * HID] + bhh[j + 3 * HID];
    float c = 0.f;
    if (j < PROJ) h_cur[j] = 0.f;
    __syncthreads();

    for (int t0 = 0; t0 < SEQ; t0 += ECH) {
        if (!L1w) {
            if (j < INF * ECH) {
                int k = j >> 2, dt = j & 3;
                xs[dt][k] = x[(size_t)b * INF * SEQ + (size_t)k * SEQ + t0 + dt];
            }
        } else {
            if (j == 0) {
                unsigned need = (unsigned)(t0 / ECH) + 1;
                while (__hip_atomic_load(&eflags[b * 16], __ATOMIC_RELAXED,
                                         __HIP_MEMORY_SCOPE_AGENT) < need)
                    __builtin_amdgcn_s_sleep(2);
            }
            __syncthreads();
            asm volatile("" ::: "memory");
            if (j < PROJ * ECH) {
                int dt = j / PROJ, p = j % PROJ;
                xs[dt][p] = gload(&H0x[((size_t)(t0 + dt) * BATCH + b) * PROJ + p]);
            }
        }
        __syncthreads();

        float a0[ECH], a1[ECH], a2[ECH], a3[ECH];
        #pragma unroll
        for (int dt = 0; dt < ECH; ++dt) { a0[dt] = bI; a1[dt] = bF; }
        for (int kq = 0; kq < K / 4; ++kq) {
            float wi0 = WT[(size_t)(kq*4+0) * G4 + j];
            float wi1 = WT[(size_t)(kq*4+1) * G4 + j];
            float wi2 = WT[(size_t)(kq*4+2) * G4 + j];
            float wi3 = WT[(size_t)(kq*4+3) * G4 + j];
            float wf0 = WT[(size_t)(kq*4+0) * G4 + HID + j];
            float wf1 = WT[(size_t)(kq*4+1) * G4 + HID + j];
            float wf2 = WT[(size_t)(kq*4+2) * G4 + HID + j];
            float wf3 = WT[(size_t)(kq*4+3) * G4 + HID + j];
            #pragma unroll
            for (int dt = 0; dt < ECH; ++dt) {
                float4 xv = *reinterpret_cast<const float4*>(&xs[dt][kq * 4]);
                a0[dt] += wi0*xv.x + wi1*xv.y + wi2*xv.z + wi3*xv.w;
                a1[dt] += wf0*xv.x + wf1*xv.y + wf2*xv.z + wf3*xv.w;
            }
        }
        #pragma unroll
        for (int dt = 0; dt < ECH; ++dt) { a2[dt] = bG; a3[dt] = bO; }
        for (int kq = 0; kq < K / 4; ++kq) {
            float wg0 = WT[(size_t)(kq*4+0) * G4 + 2 * HID + j];
            float wg1 = WT[(size_t)(kq*4+1) * G4 + 2 * HID + j];
            float wg2 = WT[(size_t)(kq*4+2) * G4 + 2 * HID + j];
            float wg3 = WT[(size_t)(kq*4+3) * G4 + 2 * HID + j];
            float wo0 = WT[(size_t)(kq*4+0) * G4 + 3 * HID + j];
            float wo1 = WT[(size_t)(kq*4+1) * G4 + 3 * HID + j];
            float wo2 = WT[(size_t)(kq*4+2) * G4 + 3 * HID + j];
            float wo3 = WT[(size_t)(kq*4+3) * G4 + 3 * HID + j];
            #pragma unroll
            for (int dt = 0; dt < ECH; ++dt) {
                float4 xv = *reinterpret_cast<const float4*>(&xs[dt][kq * 4]);
                a2[dt] += wg0*xv.x + wg1*xv.y + wg2*xv.z + wg3*xv.w;
                a3[dt] += wo0*xv.x + wo1*xv.y + wo2*xv.z + wo3*xv.w;
            }
        }

        #pragma unroll
        for (int dt = 0; dt < ECH; ++dt) {
            float ai = a0[dt], af = a1[dt], ag = a2[dt], ao = a3[dt];
            #pragma unroll
            for (int k4 = 0; k4 < 12; ++k4) {
                float4 h4 = *reinterpret_cast<const float4*>(&h_cur[4 * k4]);
                ai += wI[4*k4+0]*h4.x + wI[4*k4+1]*h4.y + wI[4*k4+2]*h4.z + wI[4*k4+3]*h4.w;
                af += wF[4*k4+0]*h4.x + wF[4*k4+1]*h4.y + wF[4*k4+2]*h4.z + wF[4*k4+3]*h4.w;
                ag += wG[4*k4+0]*h4.x + wG[4*k4+1]*h4.y + wG[4*k4+2]*h4.z + wG[4*k4+3]*h4.w;
                ao += wO[4*k4+0]*h4.x + wO[4*k4+1]*h4.y + wO[4*k4+2]*h4.z + wO[4*k4+3]*h4.w;
            }
            float si = fsigmoid(ai), sf = fsigmoid(af), so = fsigmoid(ao), tg = ftanh(ag);
            c = sf * c + si * tg;
            ht_lds[j] = so * ftanh(c);
            __syncthreads();
            float rq[6];
            #pragma unroll
            for (int q = 0; q < 6; ++q) {
                int p = wave * 6 + q;
                float s = 0.f;
                #pragma unroll
                for (int m = 0; m < 8; ++m)
                    s += whr[p][lane + 64 * m] * ht_lds[lane + 64 * m];
                #pragma unroll
                for (int o = 32; o; o >>= 1) s += __shfl_xor(s, o, 64);
                rq[q] = s;
            }
            if (lane == 0) {
                int t = t0 + dt;
                #pragma unroll
                for (int q = 0; q < 6; ++q) {
                    int p = wave * 6 + q;
                    float v = rq[q];
                    h_cur[p] = v;
                    if (!L1w) gstore(&H0x[((size_t)t * BATCH + b) * PROJ + p], v);
                    else      H1[((size_t)t * BATCH + b) * PROJ + p] = v;
                }
            }
            __syncthreads();
        }
        if (!L1w) {
            asm volatile("s_waitcnt vmcnt(0)" ::: "memory");
            __syncthreads();
            if (j == 0)
                __hip_atomic_store(&eflags[b * 16], (unsigned)(t0 / ECH) + 1,
                                   __ATOMIC_RELAXED, __HIP_MEMORY_SCOPE_AGENT);
        }
    }
    cs[((size_t)(L1w ? BATCH : 0) + b) * HID + j] = c;
    if (j < PROJ) hs[((size_t)(L1w ? BATCH : 0) + b) * PROJ + j] = h_cur[j];
}

// ---------------- persistent spill-free decoder: 64 WGs, 2 syncs/step ----------------
__global__ __launch_bounds__(512) void k_decP(
    const float* __restrict__ xdec,
    const float* __restrict__ Wih0, const float* __restrict__ Whh0,
    const float* __restrict__ bih0, const float* __restrict__ bhh0,
    const float* __restrict__ Whr0,
    const float* __restrict__ Wih1, const float* __restrict__ Whh1,
    const float* __restrict__ bih1, const float* __restrict__ bhh1,
    const float* __restrict__ Whr1,
    const float* __restrict__ hs, const float* __restrict__ cs,
    const float* __restrict__ xin,
    float* __restrict__ PPa, float* __restrict__ PPb,
    float* __restrict__ PRED,
    unsigned* __restrict__ bar)
{
    const int bg = blockIdx.x & 7, rg = blockIdx.x >> 3;
    const int tid = threadIdx.x;
    const int kq = tid & 3, rhalf = tid >> 2;
    const int u2 = tid >> 3, b2 = tid & 7;
    const int uglob = rg * DUP + u2;
    const int w = tid >> 6, lane = tid & 63;
    const size_t PSTR = (size_t)BATCH * PROJ;
    const size_t DPP  = (size_t)DRG * PSTR;

    __shared__ __align__(16) float inp0[DBP][120];
    __shared__ __align__(16) float h1b[DBP][52];
    __shared__ __align__(16) float h0n[DBP][52];
    __shared__ float xch[4][DUP][17];
    __shared__ float htl[DBP][68];
    __shared__ float wslT0[DUP][52];
    __shared__ float wslT1[DUP][52];

    for (int i = tid; i < PROJ * DUP; i += 512) {
        int p = i >> 6, uu = i & 63;
        wslT0[uu][p] = Whr0[(size_t)p * HID + rg * DUP + uu];
        wslT1[uu][p] = Whr1[(size_t)p * HID + rg * DUP + uu];
    }
    float bs0[4], bs1[4];
    #pragma unroll
    for (int gg = 0; gg < 4; ++gg) {
        bs0[gg] = bih0[gg * HID + uglob] + bhh0[gg * HID + uglob];
        bs1[gg] = bih1[gg * HID + uglob] + bhh1[gg * HID + uglob];
    }
    float c0[2], c1[2];
    #pragma unroll
    for (int hh = 0; hh < 2; ++hh) {
        int bglob = bg * DBP + b2 + 8 * hh;
        c0[hh] = cs[(size_t)bglob * HID + uglob];
        c1[hh] = cs[(size_t)(BATCH + bglob) * HID + uglob];
    }
    __syncthreads();

    unsigned* ctr = bar + bg * 64;
    unsigned phase = 0;

    for (int t = 0; t < FUT; ++t) {
        const float* ppaR = PPa + (size_t)((t - 1) & 1) * DPP;
        float*       ppaW = PPa + (size_t)(t & 1) * DPP;
        const float* ppbR = PPb + (size_t)((t - 1) & 1) * DPP;
        float*       ppbW = PPb + (size_t)(t & 1) * DPP;

        // ================= PHASE A =================
        if (t == 0) {
            for (int i = tid; i < DBP * PROJ; i += 512) {
                int b = i / PROJ, p = i % PROJ;
                int bglob = bg * DBP + b;
                inp0[b][p]      = hs[(size_t)bglob * PROJ + p];
                inp0[b][48 + p] = xin[(size_t)bglob * INF * SEQ + (size_t)p * SEQ + (SEQ - 1)];
                h1b[b][p]       = hs[(size_t)(BATCH + bglob) * PROJ + p];
            }
            if (tid < DBP * OUTF) {
                int b = tid >> 4, f = tid & 15;
                inp0[b][96 + f] = xdec[(size_t)(bg * DBP + b) * (OUTF * FUT) + (size_t)f * FUT];
            }
        } else {
            if (tid < 192) {
                int b = tid / 12, p = (tid % 12) * 4;
                int bglob = bg * DBP + b;
                f32x4 s = gsum8(ppaR + (size_t)bglob * PROJ + p, PSTR);
                *reinterpret_cast<f32x4*>(&inp0[b][p]) = s;
            } else if (tid < 384) {
                int idx = tid - 192;
                int b = idx / 12, p = (idx % 12) * 4;
                int bglob = bg * DBP + b;
                f32x4 s = gsum8(ppbR + (size_t)bglob * PROJ + p, PSTR);
                *reinterpret_cast<f32x4*>(&inp0[b][48 + p]) = s;
                *reinterpret_cast<f32x4*>(&h1b[b][p]) = s;
                if (rg == 0)
                    *reinterpret_cast<f32x4*>(&PRED[((size_t)(t - 1) * BATCH + bglob) * PROJ + p]) = s;
            } else {
                #pragma unroll
                for (int rep = 0; rep < 2; ++rep) {
                    int i2 = (tid - 384) + rep * 128;
                    int b = i2 >> 4, f = i2 & 15;
                    inp0[b][96 + f] = xdec[(size_t)(bg * DBP + b) * (OUTF * FUT) + (size_t)f * FUT + t];
                }
            }
        }
        __syncthreads();

        #pragma unroll
        for (int p = 0; p < 2; ++p) {
            int rid = p * 128 + rhalf;
            int g = rid >> 6, u = rid & 63;
            int grow = g * HID + rg * DUP + u;
            float wv[28];
            #pragma unroll
            for (int kk = 0; kk < 28; ++kk) {
                int k = kq * 28 + kk;
                wv[kk] = (k < 48) ? Whh0[(size_t)grow * 48 + k]
                                  : Wih0[(size_t)grow * 64 + (k - 48)];
            }
            float acc[DBP];
            #pragma unroll
            for (int b = 0; b < DBP; ++b) acc[b] = 0.f;
            const float* srcA = &inp0[0][0] + kq * 28;
            #pragma unroll
            for (int i4 = 0; i4 < 7; ++i4) {
                float w0 = wv[i4*4], w1 = wv[i4*4+1], w2 = wv[i4*4+2], w3 = wv[i4*4+3];
                #pragma unroll
                for (int b = 0; b < DBP; ++b) {
                    float4 xv = *reinterpret_cast<const float4*>(&srcA[b * 120 + i4 * 4]);
                    acc[b] += w0*xv.x + w1*xv.y + w2*xv.z + w3*xv.w;
                }
            }
            #pragma unroll
            for (int b = 0; b < DBP; ++b) {
                acc[b] += __shfl_xor(acc[b], 1, 64);
                acc[b] += __shfl_xor(acc[b], 2, 64);
            }
            if (kq == 0) {
                #pragma unroll
                for (int b = 0; b < DBP; ++b) xch[g][u][b] = acc[b];
            }
        }
        __syncthreads();
        #pragma unroll
        for (int hh = 0; hh < 2; ++hh) {
            int b = b2 + 8 * hh;
            float gi = xch[0][u2][b] + bs0[0];
            float gf = xch[1][u2][b] + bs0[1];
            float gc = xch[2][u2][b] + bs0[2];
            float go = xch[3][u2][b] + bs0[3];
            float si = fsigmoid(gi), sf = fsigmoid(gf), so = fsigmoid(go), tg = ftanh(gc);
            c0[hh] = sf * c0[hh] + si * tg;
            htl[b][u2] = so * ftanh(c0[hh]);
        }
        __syncthreads();
        if (lane < PROJ) {
            #pragma unroll
            for (int bb = 0; bb < 2; ++bb) {
                int b = 2 * w + bb;
                float s = 0.f;
                #pragma unroll
                for (int u4 = 0; u4 < 16; ++u4) {
                    float4 hv = *reinterpret_cast<const float4*>(&htl[b][u4 * 4]);
                    s += wslT0[u4*4+0][lane]*hv.x + wslT0[u4*4+1][lane]*hv.y
                       + wslT0[u4*4+2][lane]*hv.z + wslT0[u4*4+3][lane]*hv.w;
                }
                gstore(&ppaW[(size_t)rg * PSTR + (size_t)(bg * DBP + b) * PROJ + lane], s);
            }
        }
        phase += 1;
        bsync(ctr, phase * DRG, tid);

        // ================= PHASE B =================
        if (tid < 192) {
            int b = tid / 12, p = (tid % 12) * 4;
            f32x4 s = gsum8(ppaW + (size_t)(bg * DBP + b) * PROJ + p, PSTR);
            *reinterpret_cast<f32x4*>(&h0n[b][p]) = s;
        }
        __syncthreads();

        #pragma unroll
        for (int p = 0; p < 2; ++p) {
            int rid = p * 128 + rhalf;
            int g = rid >> 6, u = rid & 63;
            int grow = g * HID + rg * DUP + u;
            float wv[24];
            #pragma unroll
            for (int kk = 0; kk < 24; ++kk) {
                int k = kq * 24 + kk;
                wv[kk] = (k < 48) ? Whh1[(size_t)grow * 48 + k]
                                  : Wih1[(size_t)grow * 48 + (k - 48)];
            }
            const float* srcB = (kq < 2) ? (&h1b[0][0] + kq * 24)
                                         : (&h0n[0][0] + (kq - 2) * 24);
            float acc[DBP];
            #pragma unroll
            for (int b = 0; b < DBP; ++b) acc[b] = 0.f;
            #pragma unroll
            for (int i4 = 0; i4 < 6; ++i4) {
                float w0 = wv[i4*4], w1 = wv[i4*4+1], w2 = wv[i4*4+2], w3 = wv[i4*4+3];
                #pragma unroll
                for (int b = 0; b < DBP; ++b) {
                    float4 xv = *reinterpret_cast<const float4*>(&srcB[b * 52 + i4 * 4]);
                    acc[b] += w0*xv.x + w1*xv.y + w2*xv.z + w3*xv.w;
                }
            }
            #pragma unroll
            for (int b = 0; b < DBP; ++b) {
                acc[b] += __shfl_xor(acc[b], 1, 64);
                acc[b] += __shfl_xor(acc[b], 2, 64);
            }
            if (kq == 0) {
                #pragma unroll
                for (int b = 0; b < DBP; ++b) xch[g][u][b] = acc[b];
            }
        }
        __syncthreads();
        #pragma unroll
        for (int hh = 0; hh < 2; ++hh) {
            int b = b2 + 8 * hh;
            float gi = xch[0][u2][b] + bs1[0];
            float gf = xch[1][u2][b] + bs1[1];
            float gc = xch[2][u2][b] + bs1[2];
            float go = xch[3][u2][b] + bs1[3];
            float si = fsigmoid(gi), sf = fsigmoid(gf), so = fsigmoid(go), tg = ftanh(gc);
            c1[hh] = sf * c1[hh] + si * tg;
            htl[b][u2] = so * ftanh(c1[hh]);
        }
        __syncthreads();
        if (lane < PROJ) {
            #pragma unroll
            for (int bb = 0; bb < 2; ++bb) {
                int b = 2 * w + bb;
                float s = 0.f;
                #pragma unroll
                for (int u4 = 0; u4 < 16; ++u4) {
                    float4 hv = *reinterpret_cast<const float4*>(&htl[b][u4 * 4]);
                    s += wslT1[u4*4+0][lane]*hv.x + wslT1[u4*4+1][lane]*hv.y
                       + wslT1[u4*4+2][lane]*hv.z + wslT1[u4*4+3][lane]*hv.w;
                }
                gstore(&ppbW[(size_t)rg * PSTR + (size_t)(bg * DBP + b) * PROJ + lane], s);
            }
        }
        phase += 1;
        bsync(ctr, phase * DRG, tid);
    }

    if (tid < 2 * PROJ) {
        int bb = tid / PROJ, p = tid % PROJ;
        int bglob = bg * DBP + 2 * rg + bb;
        const float* ppbF = PPb + (size_t)((FUT - 1) & 1) * DPP;
        float s = 0.f;
        #pragma unroll
        for (int rr = 0; rr < DRG; ++rr)
            s += gload(&ppbF[(size_t)rr * PSTR + (size_t)bglob * PROJ + p]);
        PRED[((size_t)(FUT - 1) * BATCH + bglob) * PROJ + p] = s;
    }
}

// ---------------- basis contractions ----------------
__global__ void k_final(const float* __restrict__ theta, const float* __restrict__ H1,
                        const float* __restrict__ PRED, float* __restrict__ out)
{
    int b = blockIdx.x;
    __shared__ float th[2 * PROJ];
    if (threadIdx.x < 2 * PROJ) th[threadIdx.x] = theta[(size_t)b * 2 * PROJ + threadIdx.x];
    __syncthreads();
    for (int t = threadIdx.x; t < SEQ; t += 256) {
        float s = 0.f;
        #pragma unroll
        for (int p = 0; p < PROJ; ++p) s += th[PROJ + p] * H1[((size_t)t * BATCH + b) * PROJ + p];
        out[(size_t)b * SEQ + t] = s;
    }
    for (int t = threadIdx.x; t < FUT; t += 256) {
        float s = 0.f;
        #pragma unroll
        for (int p = 0; p < PROJ; ++p) s += th[p] * PRED[((size_t)t * BATCH + b) * PROJ + p];
        out[(size_t)BATCH * SEQ + (size_t)b * FUT + t] = s;
    }
}

extern "C" void kernel_launch(void* const* d_in, const int* in_sizes, int n_in,
                              void* d_out, int out_size, void* d_ws, size_t ws_size,
                              hipStream_t stream)
{
    (void)in_sizes; (void)n_in; (void)out_size; (void)ws_size;
    const float* theta = (const float*)d_in[0];
    const float* xin   = (const float*)d_in[1];
    const float* xdec  = (const float*)d_in[2];
    const float* eW0i = (const float*)d_in[3];
    const float* eW0h = (const float*)d_in[4];
    const float* eb0i = (const float*)d_in[5];
    const float* eb0h = (const float*)d_in[6];
    const float* eW0r = (const float*)d_in[7];
    const float* eW1i = (const float*)d_in[8];
    const float* eW1h = (const float*)d_in[9];
    const float* eb1i = (const float*)d_in[10];
    const float* eb1h = (const float*)d_in[11];
    const float* eW1r = (const float*)d_in[12];
    const float* dW0i = (const float*)d_in[13];
    const float* dW0h = (const float*)d_in[14];
    const float* db0i = (const float*)d_in[15];
    const float* db0h = (const float*)d_in[16];
    const float* dW0r = (const float*)d_in[17];
    const float* dW1i = (const float*)d_in[18];
    const float* dW1h = (const float*)d_in[19];
    const float* db1i = (const float*)d_in[20];
    const float* db1h = (const float*)d_in[21];
    const float* dW1r = (const float*)d_in[22];

    float* ws = (float*)d_ws;
    size_t off = 0;
    float* H0x  = ws + off; off += (size_t)SEQ * BATCH * PROJ;
    float* H1   = ws + off; off += (size_t)SEQ * BATCH * PROJ;
    float* PRED = ws + off; off += (size_t)FUT * BATCH * PROJ;
    float* hs   = ws + off; off += (size_t)2 * BATCH * PROJ;
    float* cs   = ws + off; off += (size_t)2 * BATCH * HID;
    float* WT0  = ws + off; off += (size_t)INF * G4;
    float* WT1  = ws + off; off += (size_t)PROJ * G4;
    const size_t DPP = (size_t)DRG * BATCH * PROJ;
    float* PPa  = ws + off; off += 2 * DPP;
    float* PPb  = ws + off; off += 2 * DPP;
    off = (off + 63) & ~(size_t)63;
    unsigned* eflags = (unsigned*)(ws + off); off += BATCH * 16;
    unsigned* bar    = (unsigned*)(ws + off); off += DBG * 64;

    hipMemsetAsync(eflags, 0, (BATCH * 16 + DBG * 64) * sizeof(unsigned), stream);
    k_wtrans<<<dim3(G4 / 32, 2), dim3(32, 8), 0, stream>>>(eW0i, WT0, G4, INF);
    k_wtrans<<<dim3(G4 / 32, 2), dim3(32, 8), 0, stream>>>(eW1i, WT1, G4, PROJ);
    k_enc<<<2 * BATCH, 512, 0, stream>>>(xin,
                                         WT0, eW0h, eb0i, eb0h, eW0r,
                                         WT1, eW1h, eb1i, eb1h, eW1r,
                                         H0x, H1, hs, cs, eflags);
    k_decP<<<DRG * DBG, 512, 0, stream>>>(xdec, dW0i, dW0h, db0i, db0h, dW0r,
                                          dW1i, dW1h, db1i, db1h, dW1r,
                                          hs, cs, xin, PPa, PPb, PRED, bar);
    k_final<<<BATCH, 256, 0, stream>>>(theta, H1, PRED, (float*)d_out);
}